// Round 1
// baseline (634.453 us; speedup 1.0000x reference)
//
#include <hip/hip_runtime.h>
#include <hip/hip_bf16.h>

#define WAVE 64

// ---------------------------------------------------------------------------
// CSR build: count incoming edges per dst, exclusive scan, fill src lists.
// Edge space is [0, E+N): first E are edge_index columns, last N self-loops.
// ---------------------------------------------------------------------------
__global__ void count_kernel(const int* __restrict__ ei, int* __restrict__ cnt,
                             int E, int N) {
    int i = blockIdx.x * blockDim.x + threadIdx.x;
    int Etot = E + N;
    if (i >= Etot) return;
    int dst = (i < E) ? ei[E + i] : (i - E);
    atomicAdd(&cnt[dst], 1);
}

__global__ void scan_kernel(const int* __restrict__ cnt, int* __restrict__ rowp,
                            int n) {
    __shared__ int wsum[16];
    __shared__ int carry_s;
    int tid = threadIdx.x, lane = tid & 63, w = tid >> 6;
    if (tid == 0) carry_s = 0;
    __syncthreads();
    for (int base = 0; base < n; base += 1024) {
        int i = base + tid;
        int v = (i < n) ? cnt[i] : 0;
        int x = v;
#pragma unroll
        for (int off = 1; off < 64; off <<= 1) {
            int t = __shfl_up(x, off, 64);
            if (lane >= off) x += t;
        }
        if (lane == 63) wsum[w] = x;
        __syncthreads();
        int wo = 0;
        for (int j = 0; j < w; ++j) wo += wsum[j];
        int carry = carry_s;
        if (i < n) rowp[i] = carry + wo + x - v;
        __syncthreads();
        if (tid == 0) {
            int tot = 0;
            for (int j = 0; j < 16; ++j) tot += wsum[j];
            carry_s = carry + tot;
        }
        __syncthreads();
    }
    if (threadIdx.x == 0) rowp[n] = carry_s;
}

__global__ void fill_kernel(const int* __restrict__ ei, const int* __restrict__ rowp,
                            int* __restrict__ cur, int* __restrict__ csrc,
                            int E, int N) {
    int i = blockIdx.x * blockDim.x + threadIdx.x;
    int Etot = E + N;
    if (i >= Etot) return;
    int src = (i < E) ? ei[i] : (i - E);
    int dst = (i < E) ? ei[E + i] : (i - E);
    int pos = rowp[dst] + atomicAdd(&cur[dst], 1);
    csrc[pos] = src;
}

// ---------------------------------------------------------------------------
// GEMM: C[M,128] = A[M,128] @ W[128,128], optional bias + relu epilogue.
// Block tile 64x128, 256 threads, each thread 4x8 outputs, K staged 32-wide.
// ---------------------------------------------------------------------------
#define GM_BM 64
#define GM_BK 32
__launch_bounds__(256)
__global__ void gemm_f32(const float* __restrict__ A, const float* __restrict__ W,
                         const float* __restrict__ bias, float* __restrict__ C,
                         int M, int relu) {
    __shared__ float As[GM_BM][GM_BK];      // 8 KB
    __shared__ float Ws[GM_BK][128 + 4];    // 16.9 KB (pad 4 -> bank shift)
    int tid = threadIdx.x;
    int row0 = blockIdx.x * GM_BM;
    int tr = tid >> 4;        // 0..15
    int tc = tid & 15;        // 0..15
    int r0 = tr * 4, c0 = tc * 8;
    float acc[4][8];
#pragma unroll
    for (int i = 0; i < 4; ++i)
#pragma unroll
        for (int j = 0; j < 8; ++j) acc[i][j] = 0.f;

    for (int kt = 0; kt < 128; kt += GM_BK) {
        // Load A tile: 64x32, thread t -> row t/4, cols (t%4)*8 .. +7
        {
            int lr = tid >> 2;
            int lc = (tid & 3) * 8;
            int gr = row0 + lr;
            float4 v0 = make_float4(0, 0, 0, 0), v1 = make_float4(0, 0, 0, 0);
            if (gr < M) {
                const float* p = A + (size_t)gr * 128 + kt + lc;
                v0 = *(const float4*)p;
                v1 = *(const float4*)(p + 4);
            }
            *(float4*)&As[lr][lc] = v0;
            *(float4*)&As[lr][lc + 4] = v1;
        }
        // Load W tile: 32x128, thread t -> row t/8, cols (t%8)*16 .. +15
        {
            int lr = tid >> 3;
            int lc = (tid & 7) * 16;
            const float* p = W + (size_t)(kt + lr) * 128 + lc;
            float4 a = *(const float4*)(p);
            float4 b = *(const float4*)(p + 4);
            float4 c = *(const float4*)(p + 8);
            float4 d = *(const float4*)(p + 12);
            *(float4*)&Ws[lr][lc] = a;
            *(float4*)&Ws[lr][lc + 4] = b;
            *(float4*)&Ws[lr][lc + 8] = c;
            *(float4*)&Ws[lr][lc + 12] = d;
        }
        __syncthreads();
        for (int k = 0; k < GM_BK; ++k) {
            float a[4];
#pragma unroll
            for (int i = 0; i < 4; ++i) a[i] = As[r0 + i][k];
            float4 w0 = *(float4*)&Ws[k][c0];
            float4 w1 = *(float4*)&Ws[k][c0 + 4];
            float wv[8] = {w0.x, w0.y, w0.z, w0.w, w1.x, w1.y, w1.z, w1.w};
#pragma unroll
            for (int i = 0; i < 4; ++i)
#pragma unroll
                for (int j = 0; j < 8; ++j) acc[i][j] += a[i] * wv[j];
        }
        __syncthreads();
    }
    // Epilogue
#pragma unroll
    for (int i = 0; i < 4; ++i) {
        int gr = row0 + r0 + i;
        if (gr >= M) continue;
        float v[8];
#pragma unroll
        for (int j = 0; j < 8; ++j) {
            float t = acc[i][j];
            if (bias) t += bias[c0 + j];
            if (relu) t = fmaxf(t, 0.f);
            v[j] = t;
        }
        float* p = C + (size_t)gr * 128 + c0;
        *(float4*)p = make_float4(v[0], v[1], v[2], v[3]);
        *(float4*)(p + 4) = make_float4(v[4], v[5], v[6], v[7]);
    }
}

// ---------------------------------------------------------------------------
// Attention logits: al_s[n,h] = <hW[n, h*C:(h+1)*C], a_src[h]>, same for dst.
// ---------------------------------------------------------------------------
__global__ void compute_al(const float* __restrict__ hW, const float* __restrict__ a_s,
                           const float* __restrict__ a_d, float* __restrict__ alS,
                           float* __restrict__ alD, int n, int heads) {
    int idx = blockIdx.x * blockDim.x + threadIdx.x;
    if (idx >= n * heads) return;
    int node = idx / heads;
    int h = idx - node * heads;
    int C = 128 / heads;
    const float* row = hW + (size_t)node * 128 + h * C;
    const float* as = a_s + h * C;
    const float* ad = a_d + h * C;
    float ss = 0.f, sd = 0.f;
    for (int c = 0; c < C; c += 4) {
        float4 rv = *(const float4*)(row + c);
        float4 sv = *(const float4*)(as + c);
        float4 dv = *(const float4*)(ad + c);
        ss += rv.x * sv.x + rv.y * sv.y + rv.z * sv.z + rv.w * sv.w;
        sd += rv.x * dv.x + rv.y * dv.y + rv.z * dv.z + rv.w * dv.w;
    }
    alS[idx] = ss;
    alD[idx] = sd;
}

// ---------------------------------------------------------------------------
// Fused GAT aggregation: one wave per dst node, online softmax over incoming
// edges, then bias (+ elu + residual) + LayerNorm, all in-wave.
// res == nullptr -> final layer (no elu/residual, just bias + LN).
// ---------------------------------------------------------------------------
__launch_bounds__(256)
__global__ void gat_aggregate(const float* __restrict__ hW,
                              const float* __restrict__ alS,
                              const float* __restrict__ alD,
                              const int* __restrict__ rowp,
                              const int* __restrict__ csrc,
                              const float* __restrict__ bias,
                              const float* __restrict__ res,
                              float* __restrict__ out,
                              int n, int heads) {
    int wid = threadIdx.x >> 6;
    int lane = threadIdx.x & 63;
    int node = blockIdx.x * 4 + wid;
    if (node >= n) return;
    int c0 = lane * 2;
    int head = (c0 * heads) >> 7;   // heads=4: c0/32; heads=1: 0
    float ald = alD[node * heads + head];
    int beg = rowp[node], end = rowp[node + 1];
    float m = -3.4e38f, z = 0.f, a0 = 0.f, a1 = 0.f;
    for (int i = beg; i < end; ++i) {
        int s = csrc[i];
        float als = alS[s * heads + head];
        float e = als + ald;
        e = (e > 0.f) ? e : 0.2f * e;
        float mn = fmaxf(m, e);
        float sc = __expf(m - mn);
        float p = __expf(e - mn);
        float2 hs = *(const float2*)(hW + (size_t)s * 128 + c0);
        z = z * sc + p;
        a0 = a0 * sc + p * hs.x;
        a1 = a1 * sc + p * hs.y;
        m = mn;
    }
    float inv = 1.f / (z + 1e-16f);
    float v0 = a0 * inv + bias[c0];
    float v1 = a1 * inv + bias[c0 + 1];
    if (res) {
        float2 rv = *(const float2*)(res + (size_t)node * 128 + c0);
        v0 = ((v0 > 0.f) ? v0 : expm1f(v0)) + rv.x;
        v1 = ((v1 > 0.f) ? v1 : expm1f(v1)) + rv.y;
    }
    // LayerNorm across the 128 channels held by this wave (2 per lane)
    float s2 = v0 + v1;
#pragma unroll
    for (int off = 1; off < 64; off <<= 1) s2 += __shfl_xor(s2, off, 64);
    float mean = s2 * (1.f / 128.f);
    float d0 = v0 - mean, d1 = v1 - mean;
    float q = d0 * d0 + d1 * d1;
#pragma unroll
    for (int off = 1; off < 64; off <<= 1) q += __shfl_xor(q, off, 64);
    float r = rsqrtf(q * (1.f / 128.f) + 1e-5f);
    float2 o;
    o.x = d0 * r;
    o.y = d1 * r;
    *(float2*)(out + (size_t)node * 128 + c0) = o;
}

// ---------------------------------------------------------------------------
extern "C" void kernel_launch(void* const* d_in, const int* in_sizes, int n_in,
                              void* d_out, int out_size, void* d_ws, size_t ws_size,
                              hipStream_t stream) {
    const int N = in_sizes[0] / 128;
    const int E = in_sizes[1] / 2;
    const int Etot = E + N;

    const float* x    = (const float*)d_in[0];
    const int*   ei   = (const int*)d_in[1];
    const float* W_in = (const float*)d_in[2];
    const float* b_in = (const float*)d_in[3];
    const float* W0   = (const float*)d_in[4];
    const float* as0  = (const float*)d_in[5];
    const float* ad0  = (const float*)d_in[6];
    const float* b0   = (const float*)d_in[7];
    const float* W1   = (const float*)d_in[8];
    const float* as1  = (const float*)d_in[9];
    const float* ad1  = (const float*)d_in[10];
    const float* b1   = (const float*)d_in[11];
    const float* W2   = (const float*)d_in[12];
    const float* as2  = (const float*)d_in[13];
    const float* ad2  = (const float*)d_in[14];
    const float* b2   = (const float*)d_in[15];

    char* wsp = (char*)d_ws;
    size_t off = 0;
    auto carve = [&](size_t bytes) -> void* {
        void* p = wsp + off;
        off += (bytes + 255) & ~(size_t)255;
        return p;
    };
    float* hA   = (float*)carve((size_t)N * 128 * 4);
    float* hB   = (float*)carve((size_t)N * 128 * 4);
    float* hW   = (float*)carve((size_t)N * 128 * 4);
    float* alS  = (float*)carve((size_t)N * 4 * 4);
    float* alD  = (float*)carve((size_t)N * 4 * 4);
    int*   cnt  = (int*)carve((size_t)2 * N * 4);
    int*   cur  = cnt + N;
    int*   rowp = (int*)carve((size_t)(N + 1) * 4);
    int*   csrc = (int*)carve((size_t)Etot * 4);
    (void)ws_size; (void)n_in; (void)out_size;

    hipMemsetAsync(cnt, 0, (size_t)2 * N * 4, stream);
    count_kernel<<<(Etot + 255) / 256, 256, 0, stream>>>(ei, cnt, E, N);
    scan_kernel<<<1, 1024, 0, stream>>>(cnt, rowp, N);
    fill_kernel<<<(Etot + 255) / 256, 256, 0, stream>>>(ei, rowp, cur, csrc, E, N);

    int gg = (N + GM_BM - 1) / GM_BM;
    // h = relu(x @ W_in + b_in)
    gemm_f32<<<gg, 256, 0, stream>>>(x, W_in, b_in, hA, N, 1);

    // Layer 0
    gemm_f32<<<gg, 256, 0, stream>>>(hA, W0, nullptr, hW, N, 0);
    compute_al<<<(N * 4 + 255) / 256, 256, 0, stream>>>(hW, as0, ad0, alS, alD, N, 4);
    gat_aggregate<<<(N + 3) / 4, 256, 0, stream>>>(hW, alS, alD, rowp, csrc, b0, hA, hB, N, 4);

    // Layer 1
    gemm_f32<<<gg, 256, 0, stream>>>(hB, W1, nullptr, hW, N, 0);
    compute_al<<<(N * 4 + 255) / 256, 256, 0, stream>>>(hW, as1, ad1, alS, alD, N, 4);
    gat_aggregate<<<(N + 3) / 4, 256, 0, stream>>>(hW, alS, alD, rowp, csrc, b1, hB, hA, N, 4);

    // Layer 2 (heads=1, mean==identity, bias + LN only)
    gemm_f32<<<gg, 256, 0, stream>>>(hA, W2, nullptr, hW, N, 0);
    compute_al<<<(N + 255) / 256, 256, 0, stream>>>(hW, as2, ad2, alS, alD, N, 1);
    gat_aggregate<<<(N + 3) / 4, 256, 0, stream>>>(hW, alS, alD, rowp, csrc, b2, nullptr,
                                                   (float*)d_out, N, 1);
}

// Round 2
// 399.302 us; speedup vs baseline: 1.5889x; 1.5889x over previous
//
#include <hip/hip_runtime.h>
#include <hip/hip_bf16.h>

typedef unsigned short ushort_t;
typedef unsigned int uint_t;

__device__ __forceinline__ ushort_t f2bf(float f) {
    uint_t u = __float_as_uint(f);
    uint_t r = (u + 0x7FFFu + ((u >> 16) & 1u)) >> 16;
    return (ushort_t)r;
}

// ---------------------------------------------------------------------------
// CSR build
// ---------------------------------------------------------------------------
__global__ void count_kernel(const int* __restrict__ ei, int* __restrict__ cnt,
                             int E, int N) {
    int i = blockIdx.x * blockDim.x + threadIdx.x;
    int Etot = E + N;
    if (i >= Etot) return;
    int dst = (i < E) ? ei[E + i] : (i - E);
    atomicAdd(&cnt[dst], 1);
}

__global__ void fill_kernel(const int* __restrict__ ei, const int* __restrict__ rowp,
                            int* __restrict__ cur, int* __restrict__ csrc,
                            int E, int N) {
    int i = blockIdx.x * blockDim.x + threadIdx.x;
    int Etot = E + N;
    if (i >= Etot) return;
    int src = (i < E) ? ei[i] : (i - E);
    int dst = (i < E) ? ei[E + i] : (i - E);
    int pos = rowp[dst] + atomicAdd(&cur[dst], 1);
    csrc[pos] = src;
}

// Multi-block exclusive scan over cnt[0..n) -> rowp[0..n]
#define SCH 512
__global__ void scan_part(const int* __restrict__ cnt, int* __restrict__ part, int n) {
    int b = blockIdx.x;
    int i0 = b * SCH + threadIdx.x;
    int v = 0;
    if (i0 < n) v += cnt[i0];
    if (i0 + 256 < (b + 1) * SCH && i0 + 256 < n) v += cnt[i0 + 256];
#pragma unroll
    for (int off = 1; off < 64; off <<= 1) v += __shfl_xor(v, off, 64);
    __shared__ int ws[4];
    if ((threadIdx.x & 63) == 0) ws[threadIdx.x >> 6] = v;
    __syncthreads();
    if (threadIdx.x == 0) part[b] = ws[0] + ws[1] + ws[2] + ws[3];
}

__global__ void scan_aux(int* __restrict__ part, int nb) {
    int t = threadIdx.x;
    int lane = t & 63, w = t >> 6;
    int v = (t < nb) ? part[t] : 0;
    int x = v;
#pragma unroll
    for (int off = 1; off < 64; off <<= 1) {
        int t2 = __shfl_up(x, off, 64);
        if (lane >= off) x += t2;
    }
    __shared__ int ws2[4];
    if (lane == 63) ws2[w] = x;
    __syncthreads();
    int add = 0;
    for (int j = 0; j < w; ++j) add += ws2[j];
    if (t < nb) part[t] = add + x - v;   // exclusive
}

__global__ void scan_apply(const int* __restrict__ cnt, const int* __restrict__ part,
                           int* __restrict__ rowp, int n) {
    int b = blockIdx.x;
    int t = threadIdx.x;
    int base = b * SCH;
    int i0 = base + 2 * t, i1 = i0 + 1;
    int x0 = (i0 < n) ? cnt[i0] : 0;
    int x1 = (i1 < n) ? cnt[i1] : 0;
    int pairs = x0 + x1;
    int lane = t & 63, w = t >> 6;
    int x = pairs;
#pragma unroll
    for (int off = 1; off < 64; off <<= 1) {
        int t2 = __shfl_up(x, off, 64);
        if (lane >= off) x += t2;
    }
    __shared__ int ws3[4];
    if (lane == 63) ws3[w] = x;
    __syncthreads();
    int add = part[b];
    for (int j = 0; j < w; ++j) add += ws3[j];
    int excl = add + x - pairs;
    if (i0 <= n) rowp[i0] = excl;
    if (i1 <= n) rowp[i1] = excl + x0;
}

// ---------------------------------------------------------------------------
// GEMM: C[M,128] = A[M,128] @ W[128,128]
// MODE 0: f32 out, +bias, relu.
// MODE 1: bf16 out + fused attention logits (heads=4).
// MODE 2: bf16 out + fused attention logits (heads=1).
// ---------------------------------------------------------------------------
#define GM_BM 64
#define GM_BK 32
template <int MODE>
__launch_bounds__(256)
__global__ void gemm_f32(const float* __restrict__ A, const float* __restrict__ W,
                         const float* __restrict__ bias, float* __restrict__ C,
                         ushort_t* __restrict__ Cb,
                         const float* __restrict__ a_s, const float* __restrict__ a_d,
                         float* __restrict__ alS, float* __restrict__ alD, int M) {
    __shared__ float As[GM_BM][GM_BK];
    __shared__ float Ws[GM_BK][128 + 4];
    int tid = threadIdx.x;
    int row0 = blockIdx.x * GM_BM;
    int tr = tid >> 4;
    int tc = tid & 15;
    int r0 = tr * 4, c0 = tc * 8;
    float acc[4][8];
#pragma unroll
    for (int i = 0; i < 4; ++i)
#pragma unroll
        for (int j = 0; j < 8; ++j) acc[i][j] = 0.f;

    for (int kt = 0; kt < 128; kt += GM_BK) {
        {
            int lr = tid >> 2;
            int lc = (tid & 3) * 8;
            int gr = row0 + lr;
            float4 v0 = make_float4(0, 0, 0, 0), v1 = make_float4(0, 0, 0, 0);
            if (gr < M) {
                const float* p = A + (size_t)gr * 128 + kt + lc;
                v0 = *(const float4*)p;
                v1 = *(const float4*)(p + 4);
            }
            *(float4*)&As[lr][lc] = v0;
            *(float4*)&As[lr][lc + 4] = v1;
        }
        {
            int lr = tid >> 3;
            int lc = (tid & 7) * 16;
            const float* p = W + (size_t)(kt + lr) * 128 + lc;
            float4 a = *(const float4*)(p);
            float4 b = *(const float4*)(p + 4);
            float4 c = *(const float4*)(p + 8);
            float4 d = *(const float4*)(p + 12);
            *(float4*)&Ws[lr][lc] = a;
            *(float4*)&Ws[lr][lc + 4] = b;
            *(float4*)&Ws[lr][lc + 8] = c;
            *(float4*)&Ws[lr][lc + 12] = d;
        }
        __syncthreads();
        for (int k = 0; k < GM_BK; ++k) {
            float a[4];
#pragma unroll
            for (int i = 0; i < 4; ++i) a[i] = As[r0 + i][k];
            float4 w0 = *(float4*)&Ws[k][c0];
            float4 w1 = *(float4*)&Ws[k][c0 + 4];
            float wv[8] = {w0.x, w0.y, w0.z, w0.w, w1.x, w1.y, w1.z, w1.w};
#pragma unroll
            for (int i = 0; i < 4; ++i)
#pragma unroll
                for (int j = 0; j < 8; ++j) acc[i][j] += a[i] * wv[j];
        }
        __syncthreads();
    }

    if (MODE == 0) {
#pragma unroll
        for (int i = 0; i < 4; ++i) {
            int gr = row0 + r0 + i;
            if (gr >= M) continue;
            float v[8];
#pragma unroll
            for (int j = 0; j < 8; ++j) {
                float t = acc[i][j] + bias[c0 + j];
                v[j] = fmaxf(t, 0.f);
            }
            float* p = C + (size_t)gr * 128 + c0;
            *(float4*)p = make_float4(v[0], v[1], v[2], v[3]);
            *(float4*)(p + 4) = make_float4(v[4], v[5], v[6], v[7]);
        }
    } else {
        const int HEADS = (MODE == 1) ? 4 : 1;
        const int G = 16 / HEADS;            // threads per (row, head)
        int head = tc / G;
        float as8[8], ad8[8];
#pragma unroll
        for (int j = 0; j < 8; ++j) {
            as8[j] = a_s[c0 + j];
            ad8[j] = a_d[c0 + j];
        }
        float ps[4], pd[4];
#pragma unroll
        for (int i = 0; i < 4; ++i) {
            float s = 0.f, d = 0.f;
#pragma unroll
            for (int j = 0; j < 8; ++j) {
                s += acc[i][j] * as8[j];
                d += acc[i][j] * ad8[j];
            }
            ps[i] = s;
            pd[i] = d;
        }
#pragma unroll
        for (int off = 1; off < G; off <<= 1) {
#pragma unroll
            for (int i = 0; i < 4; ++i) {
                ps[i] += __shfl_xor(ps[i], off, 64);
                pd[i] += __shfl_xor(pd[i], off, 64);
            }
        }
        if ((tc & (G - 1)) == 0) {
#pragma unroll
            for (int i = 0; i < 4; ++i) {
                int gr = row0 + r0 + i;
                if (gr < M) {
                    alS[gr * HEADS + head] = ps[i];
                    alD[gr * HEADS + head] = pd[i];
                }
            }
        }
#pragma unroll
        for (int i = 0; i < 4; ++i) {
            int gr = row0 + r0 + i;
            if (gr >= M) continue;
            uint_t pk[4];
#pragma unroll
            for (int jj = 0; jj < 4; ++jj) {
                pk[jj] = (uint_t)f2bf(acc[i][2 * jj]) |
                         ((uint_t)f2bf(acc[i][2 * jj + 1]) << 16);
            }
            uint4 u;
            u.x = pk[0]; u.y = pk[1]; u.z = pk[2]; u.w = pk[3];
            *(uint4*)(Cb + (size_t)gr * 128 + c0) = u;
        }
    }
}

// ---------------------------------------------------------------------------
// Fused GAT aggregation, edge-parallel two-phase per wave.
// Phase 1: lanes own edges; compute e per head from one alS gather, wave-reduce
//          max and sum of exp, stash per-edge p in wave-private LDS.
// Phase 2: independent weighted bf16 gather, unrolled.
// Epilogue: bias (+elu+residual) + in-wave LayerNorm.
// ---------------------------------------------------------------------------
template <int H>
__launch_bounds__(256)
__global__ void gat_aggregate(const ushort_t* __restrict__ hWb,
                              const float* __restrict__ alS,
                              const float* __restrict__ alD,
                              const int* __restrict__ rowp,
                              const int* __restrict__ csrc,
                              const float* __restrict__ bias,
                              const float* __restrict__ res,
                              float* __restrict__ out, int n) {
    __shared__ float pbuf[4][64][4];
    __shared__ int sbuf[4][64];
    int wid = threadIdx.x >> 6;
    int lane = threadIdx.x & 63;
    int node = blockIdx.x * 4 + wid;
    if (node >= n) return;
    int c0 = lane * 2;
    float ald[H];
    if (H == 4) {
        float4 t = *(const float4*)(alD + (size_t)node * 4);
        ald[0] = t.x;
        if (H > 1) { ald[1] = t.y; ald[2] = t.z; ald[3] = t.w; }
    } else {
        ald[0] = alD[node];
    }
    int beg = rowp[node], end = rowp[node + 1];
    float m[H], z[H];
#pragma unroll
    for (int h = 0; h < H; ++h) { m[h] = -3.4e38f; z[h] = 0.f; }
    float a0 = 0.f, a1 = 0.f;

    for (int base = beg; base < end; base += 64) {
        int nc = min(64, end - base);
        bool act = lane < nc;
        int s = 0;
        float e[H];
        if (act) {
            s = csrc[base + lane];
            if (H == 4) {
                float4 t = *(const float4*)(alS + (size_t)s * 4);
                float v[4] = {t.x, t.y, t.z, t.w};
#pragma unroll
                for (int h = 0; h < 4; ++h) {
                    float x = v[h] + ald[h];
                    e[h] = (x > 0.f) ? x : 0.2f * x;
                }
            } else {
                float x = alS[s] + ald[0];
                e[0] = (x > 0.f) ? x : 0.2f * x;
            }
        } else {
#pragma unroll
            for (int h = 0; h < H; ++h) e[h] = -3.4e38f;
        }
        // chunk max per head
        float cm[H];
#pragma unroll
        for (int h = 0; h < H; ++h) cm[h] = e[h];
#pragma unroll
        for (int off = 1; off < 64; off <<= 1)
#pragma unroll
            for (int h = 0; h < H; ++h) cm[h] = fmaxf(cm[h], __shfl_xor(cm[h], off, 64));
        float nm[H], sc[H], p[H], zc[H];
#pragma unroll
        for (int h = 0; h < H; ++h) {
            nm[h] = fmaxf(m[h], cm[h]);
            sc[h] = __expf(m[h] - nm[h]);
            p[h] = act ? __expf(e[h] - nm[h]) : 0.f;
            zc[h] = p[h];
        }
#pragma unroll
        for (int off = 1; off < 64; off <<= 1)
#pragma unroll
            for (int h = 0; h < H; ++h) zc[h] += __shfl_xor(zc[h], off, 64);
#pragma unroll
        for (int h = 0; h < H; ++h) {
            z[h] = z[h] * sc[h] + zc[h];
            m[h] = nm[h];
        }
        float mysc;
        if (H == 1) mysc = sc[0];
        else mysc = (lane & 32) ? ((lane & 16) ? sc[3] : sc[2])
                                : ((lane & 16) ? sc[1] : sc[0]);
        a0 *= mysc;
        a1 *= mysc;
        if (act) {
            sbuf[wid][lane] = s;
            if (H == 4) {
                float4 t4;
                t4.x = p[0]; t4.y = p[1]; t4.z = p[2]; t4.w = p[3];
                *(float4*)&pbuf[wid][lane][0] = t4;
            } else {
                pbuf[wid][lane][0] = p[0];
            }
        }
        // phase 2: weighted gather (wave-private LDS, no barrier needed)
        int head4 = (H == 4) ? (lane >> 4) : 0;
        int i = 0;
        for (; i + 2 <= nc; i += 2) {
            int s0 = sbuf[wid][i];
            int s1 = sbuf[wid][i + 1];
            float p0 = pbuf[wid][i][head4];
            float p1 = pbuf[wid][i + 1][head4];
            uint_t h0 = ((const uint_t*)(hWb + ((size_t)s0 << 7)))[lane];
            uint_t h1 = ((const uint_t*)(hWb + ((size_t)s1 << 7)))[lane];
            a0 += p0 * __uint_as_float(h0 << 16);
            a1 += p0 * __uint_as_float(h0 & 0xffff0000u);
            a0 += p1 * __uint_as_float(h1 << 16);
            a1 += p1 * __uint_as_float(h1 & 0xffff0000u);
        }
        if (i < nc) {
            int s0 = sbuf[wid][i];
            float p0 = pbuf[wid][i][head4];
            uint_t h0 = ((const uint_t*)(hWb + ((size_t)s0 << 7)))[lane];
            a0 += p0 * __uint_as_float(h0 << 16);
            a1 += p0 * __uint_as_float(h0 & 0xffff0000u);
        }
    }

    float zv;
    if (H == 1) zv = z[0];
    else zv = (lane & 32) ? ((lane & 16) ? z[3] : z[2])
                          : ((lane & 16) ? z[1] : z[0]);
    float inv = 1.f / (zv + 1e-16f);
    float v0 = a0 * inv + bias[c0];
    float v1 = a1 * inv + bias[c0 + 1];
    if (res) {
        float2 rv = *(const float2*)(res + (size_t)node * 128 + c0);
        v0 = ((v0 > 0.f) ? v0 : expm1f(v0)) + rv.x;
        v1 = ((v1 > 0.f) ? v1 : expm1f(v1)) + rv.y;
    }
    float s2 = v0 + v1;
#pragma unroll
    for (int off = 1; off < 64; off <<= 1) s2 += __shfl_xor(s2, off, 64);
    float mean = s2 * (1.f / 128.f);
    float d0 = v0 - mean, d1 = v1 - mean;
    float q = d0 * d0 + d1 * d1;
#pragma unroll
    for (int off = 1; off < 64; off <<= 1) q += __shfl_xor(q, off, 64);
    float r = rsqrtf(q * (1.f / 128.f) + 1e-5f);
    float2 o;
    o.x = d0 * r;
    o.y = d1 * r;
    *(float2*)(out + (size_t)node * 128 + c0) = o;
}

// ---------------------------------------------------------------------------
extern "C" void kernel_launch(void* const* d_in, const int* in_sizes, int n_in,
                              void* d_out, int out_size, void* d_ws, size_t ws_size,
                              hipStream_t stream) {
    const int N = in_sizes[0] / 128;
    const int E = in_sizes[1] / 2;
    const int Etot = E + N;

    const float* x    = (const float*)d_in[0];
    const int*   ei   = (const int*)d_in[1];
    const float* W_in = (const float*)d_in[2];
    const float* b_in = (const float*)d_in[3];
    const float* W0   = (const float*)d_in[4];
    const float* as0  = (const float*)d_in[5];
    const float* ad0  = (const float*)d_in[6];
    const float* b0   = (const float*)d_in[7];
    const float* W1   = (const float*)d_in[8];
    const float* as1  = (const float*)d_in[9];
    const float* ad1  = (const float*)d_in[10];
    const float* b1   = (const float*)d_in[11];
    const float* W2   = (const float*)d_in[12];
    const float* as2  = (const float*)d_in[13];
    const float* ad2  = (const float*)d_in[14];
    const float* b2   = (const float*)d_in[15];

    char* wsp = (char*)d_ws;
    size_t off = 0;
    auto carve = [&](size_t bytes) -> void* {
        void* p = wsp + off;
        off += (bytes + 255) & ~(size_t)255;
        return p;
    };
    float*    hA   = (float*)carve((size_t)N * 128 * 4);
    float*    hB   = (float*)carve((size_t)N * 128 * 4);
    ushort_t* hWb  = (ushort_t*)carve((size_t)N * 128 * 2);
    float*    alS  = (float*)carve((size_t)N * 4 * 4);
    float*    alD  = (float*)carve((size_t)N * 4 * 4);
    int*      cnt  = (int*)carve((size_t)2 * N * 4);
    int*      cur  = cnt + N;
    int*      rowp = (int*)carve((size_t)(N + 1) * 4);
    int*      csrc = (int*)carve((size_t)Etot * 4);
    int*      part = (int*)carve((size_t)1024 * 4);
    (void)ws_size; (void)n_in; (void)out_size;

    const int nb = (N + SCH - 1) / SCH;
    const int nb2 = (N + 1 + SCH - 1) / SCH;

    hipMemsetAsync(cnt, 0, (size_t)2 * N * 4, stream);
    count_kernel<<<(Etot + 255) / 256, 256, 0, stream>>>(ei, cnt, E, N);
    scan_part<<<nb, 256, 0, stream>>>(cnt, part, N);
    scan_aux<<<1, 256, 0, stream>>>(part, nb);
    scan_apply<<<nb2, 256, 0, stream>>>(cnt, part, rowp, N);
    fill_kernel<<<(Etot + 255) / 256, 256, 0, stream>>>(ei, rowp, cur, csrc, E, N);

    int gg = (N + GM_BM - 1) / GM_BM;
    int ga = (N + 3) / 4;

    // h = relu(x @ W_in + b_in)
    gemm_f32<0><<<gg, 256, 0, stream>>>(x, W_in, b_in, hA, nullptr,
                                        nullptr, nullptr, nullptr, nullptr, N);
    // Layer 0
    gemm_f32<1><<<gg, 256, 0, stream>>>(hA, W0, nullptr, nullptr, hWb,
                                        as0, ad0, alS, alD, N);
    gat_aggregate<4><<<ga, 256, 0, stream>>>(hWb, alS, alD, rowp, csrc, b0, hA, hB, N);
    // Layer 1
    gemm_f32<1><<<gg, 256, 0, stream>>>(hB, W1, nullptr, nullptr, hWb,
                                        as1, ad1, alS, alD, N);
    gat_aggregate<4><<<ga, 256, 0, stream>>>(hWb, alS, alD, rowp, csrc, b1, hB, hA, N);
    // Layer 2 (heads=1)
    gemm_f32<2><<<gg, 256, 0, stream>>>(hA, W2, nullptr, nullptr, hWb,
                                        as2, ad2, alS, alD, N);
    gat_aggregate<1><<<ga, 256, 0, stream>>>(hWb, alS, alD, rowp, csrc, b2, nullptr,
                                             (float*)d_out, N);
}

// Round 3
// 343.232 us; speedup vs baseline: 1.8485x; 1.1634x over previous
//
#include <hip/hip_runtime.h>
#include <hip/hip_bf16.h>

typedef unsigned short ushort_t;
typedef unsigned int uint_t;
typedef __attribute__((ext_vector_type(8))) short short8;
typedef __attribute__((ext_vector_type(4))) float f32x4;

__device__ __forceinline__ ushort_t f2bf(float f) {
    uint_t u = __float_as_uint(f);
    uint_t r = (u + 0x7FFFu + ((u >> 16) & 1u)) >> 16;
    return (ushort_t)r;
}
__device__ __forceinline__ float bf2f_lo(uint_t u) { return __uint_as_float(u << 16); }
__device__ __forceinline__ float bf2f_hi(uint_t u) { return __uint_as_float(u & 0xffff0000u); }

// ---------------------------------------------------------------------------
// CSR build
// ---------------------------------------------------------------------------
__global__ void count_kernel(const int* __restrict__ ei, int* __restrict__ cnt,
                             int E, int N) {
    int i = blockIdx.x * blockDim.x + threadIdx.x;
    int Etot = E + N;
    if (i >= Etot) return;
    int dst = (i < E) ? ei[E + i] : (i - E);
    atomicAdd(&cnt[dst], 1);
}

__global__ void fill_kernel(const int* __restrict__ ei, const int* __restrict__ rowp,
                            int* __restrict__ cur, int* __restrict__ csrc,
                            int E, int N) {
    int i = blockIdx.x * blockDim.x + threadIdx.x;
    int Etot = E + N;
    if (i >= Etot) return;
    int src = (i < E) ? ei[i] : (i - E);
    int dst = (i < E) ? ei[E + i] : (i - E);
    int pos = rowp[dst] + atomicAdd(&cur[dst], 1);
    csrc[pos] = src;
}

#define SCH 512
__global__ void scan_part(const int* __restrict__ cnt, int* __restrict__ part, int n) {
    int b = blockIdx.x;
    int i0 = b * SCH + threadIdx.x;
    int v = 0;
    if (i0 < n) v += cnt[i0];
    if (i0 + 256 < (b + 1) * SCH && i0 + 256 < n) v += cnt[i0 + 256];
#pragma unroll
    for (int off = 1; off < 64; off <<= 1) v += __shfl_xor(v, off, 64);
    __shared__ int ws[4];
    if ((threadIdx.x & 63) == 0) ws[threadIdx.x >> 6] = v;
    __syncthreads();
    if (threadIdx.x == 0) part[b] = ws[0] + ws[1] + ws[2] + ws[3];
}

__global__ void scan_aux(int* __restrict__ part, int nb) {
    int t = threadIdx.x;
    int lane = t & 63, w = t >> 6;
    int v = (t < nb) ? part[t] : 0;
    int x = v;
#pragma unroll
    for (int off = 1; off < 64; off <<= 1) {
        int t2 = __shfl_up(x, off, 64);
        if (lane >= off) x += t2;
    }
    __shared__ int ws2[4];
    if (lane == 63) ws2[w] = x;
    __syncthreads();
    int add = 0;
    for (int j = 0; j < w; ++j) add += ws2[j];
    if (t < nb) part[t] = add + x - v;
}

__global__ void scan_apply(const int* __restrict__ cnt, const int* __restrict__ part,
                           int* __restrict__ rowp, int n) {
    int b = blockIdx.x;
    int t = threadIdx.x;
    int base = b * SCH;
    int i0 = base + 2 * t, i1 = i0 + 1;
    int x0 = (i0 < n) ? cnt[i0] : 0;
    int x1 = (i1 < n) ? cnt[i1] : 0;
    int pairs = x0 + x1;
    int lane = t & 63, w = t >> 6;
    int x = pairs;
#pragma unroll
    for (int off = 1; off < 64; off <<= 1) {
        int t2 = __shfl_up(x, off, 64);
        if (lane >= off) x += t2;
    }
    __shared__ int ws3[4];
    if (lane == 63) ws3[w] = x;
    __syncthreads();
    int add = part[b];
    for (int j = 0; j < w; ++j) add += ws3[j];
    int excl = add + x - pairs;
    if (i0 <= n) rowp[i0] = excl;
    if (i1 <= n) rowp[i1] = excl + x0;
}

// ---------------------------------------------------------------------------
// Pre-pack B fragments in MFMA layout: [kstep(4)][ntile(NT)][lane(64)][8 bf16]
// ntile 0..7  : W columns nt*16 + (lane&15), k = kstep*32 + (lane>>4)*8 + j
// ntile 8 (H>0): logit columns. H=4: col 0..3 = Vs[head], col 4..7 = Vd[head],
//                Vs[k][h] = sum_c W[k][h*32+c]*a_s[h*32+c]. H=1: col0=Vs,col1=Vd.
// ---------------------------------------------------------------------------
template <int H>
__global__ void build_bfrag(const float* __restrict__ W, const float* __restrict__ a_s,
                            const float* __restrict__ a_d, ushort_t* __restrict__ Bf) {
    const int NT = (H > 0) ? 9 : 8;
    int l = threadIdx.x & 63;
    int ks = threadIdx.x >> 6;
    int kb = ks * 32 + (l >> 4) * 8;
    int col = l & 15;
    for (int nt = 0; nt < 8; ++nt) {
        ushort_t v[8];
#pragma unroll
        for (int j = 0; j < 8; ++j)
            v[j] = f2bf(W[(size_t)(kb + j) * 128 + nt * 16 + col]);
        uint4 u;
        u.x = (uint_t)v[0] | ((uint_t)v[1] << 16);
        u.y = (uint_t)v[2] | ((uint_t)v[3] << 16);
        u.z = (uint_t)v[4] | ((uint_t)v[5] << 16);
        u.w = (uint_t)v[6] | ((uint_t)v[7] << 16);
        *(uint4*)(Bf + ((size_t)(ks * NT + nt) * 64 + l) * 8) = u;
    }
    if (H > 0) {
        ushort_t v[8];
        for (int j = 0; j < 8; ++j) {
            int k = kb + j;
            float s = 0.f;
            if (H == 4) {
                if (col < 4) {
                    for (int c = 0; c < 32; ++c)
                        s += W[(size_t)k * 128 + col * 32 + c] * a_s[col * 32 + c];
                } else if (col < 8) {
                    int h = col - 4;
                    for (int c = 0; c < 32; ++c)
                        s += W[(size_t)k * 128 + h * 32 + c] * a_d[h * 32 + c];
                }
            } else {
                if (col == 0) {
                    for (int c = 0; c < 128; ++c) s += W[(size_t)k * 128 + c] * a_s[c];
                } else if (col == 1) {
                    for (int c = 0; c < 128; ++c) s += W[(size_t)k * 128 + c] * a_d[c];
                }
            }
            v[j] = f2bf(s);
        }
        uint4 u;
        u.x = (uint_t)v[0] | ((uint_t)v[1] << 16);
        u.y = (uint_t)v[2] | ((uint_t)v[3] << 16);
        u.z = (uint_t)v[4] | ((uint_t)v[5] << 16);
        u.w = (uint_t)v[6] | ((uint_t)v[7] << 16);
        *(uint4*)(Bf + ((size_t)(ks * NT + 8) * 64 + l) * 8) = u;
    }
}

// ---------------------------------------------------------------------------
// MFMA GEMM: one 16-row tile per wave, K=128, N-tiles = 8 (+1 logit tile).
// MODE 0: A = f32 (x), epilogue bias+relu -> bf16 out.
// MODE 1: A = bf16, out bf16 + alS/alD (heads=4) from tile 8.
// MODE 2: same, heads=1.
// ---------------------------------------------------------------------------
template <int MODE>
__launch_bounds__(256)
__global__ void gemm_mfma(const float* __restrict__ Af, const ushort_t* __restrict__ Ab,
                          const ushort_t* __restrict__ Bf, const float* __restrict__ bias,
                          ushort_t* __restrict__ outB, float* __restrict__ alS,
                          float* __restrict__ alD, int M) {
    const int NT = (MODE == 0) ? 8 : 9;
    int wid = threadIdx.x >> 6, l = threadIdx.x & 63;
    int t = blockIdx.x * 4 + wid;
    int r0 = t * 16;
    if (r0 >= M) return;
    int lg = l >> 4, lc = l & 15;
    f32x4 acc[9];
#pragma unroll
    for (int nt = 0; nt < NT; ++nt) acc[nt] = (f32x4){0.f, 0.f, 0.f, 0.f};

#pragma unroll
    for (int ks = 0; ks < 4; ++ks) {
        int k0 = ks * 32 + lg * 8;
        short8 af;
        if (MODE == 0) {
            const float* ap = Af + (size_t)(r0 + lc) * 128 + k0;
            float4 x0 = *(const float4*)ap;
            float4 x1 = *(const float4*)(ap + 4);
            af[0] = (short)f2bf(x0.x);
            af[1] = (short)f2bf(x0.y);
            af[2] = (short)f2bf(x0.z);
            af[3] = (short)f2bf(x0.w);
            af[4] = (short)f2bf(x1.x);
            af[5] = (short)f2bf(x1.y);
            af[6] = (short)f2bf(x1.z);
            af[7] = (short)f2bf(x1.w);
        } else {
            af = *(const short8*)(Ab + (size_t)(r0 + lc) * 128 + k0);
        }
#pragma unroll
        for (int nt = 0; nt < NT; ++nt) {
            short8 bfr = *(const short8*)(Bf + ((size_t)(ks * NT + nt) * 64 + l) * 8);
            acc[nt] = __builtin_amdgcn_mfma_f32_16x16x32_bf16(af, bfr, acc[nt], 0, 0, 0);
        }
    }

    if (MODE == 0) {
        float bv[8];
#pragma unroll
        for (int nt = 0; nt < 8; ++nt) bv[nt] = bias[nt * 16 + lc];
#pragma unroll
        for (int r = 0; r < 4; ++r) {
            int row = r0 + lg * 4 + r;
            ushort_t* op = outB + (size_t)row * 128 + lc;
#pragma unroll
            for (int nt = 0; nt < 8; ++nt) {
                float v = fmaxf(acc[nt][r] + bv[nt], 0.f);
                op[nt * 16] = f2bf(v);
            }
        }
    } else {
#pragma unroll
        for (int r = 0; r < 4; ++r) {
            int row = r0 + lg * 4 + r;
            ushort_t* op = outB + (size_t)row * 128 + lc;
#pragma unroll
            for (int nt = 0; nt < 8; ++nt) op[nt * 16] = f2bf(acc[nt][r]);
            float lv = acc[8][r];
            if (MODE == 1) {
                if (lc < 4) alS[(size_t)row * 4 + lc] = lv;
                else if (lc < 8) alD[(size_t)row * 4 + (lc - 4)] = lv;
            } else {
                if (lc == 0) alS[row] = lv;
                else if (lc == 1) alD[row] = lv;
            }
        }
    }
}

// ---------------------------------------------------------------------------
// Fused GAT aggregation, no-max softmax (logits are tiny: exp is safe in f32
// and exp(e)/sum(exp(e)) == exp(e-m)/sum(exp(e-m)) exactly in math).
// Phase 1: lanes own edges; p = exp(leaky(alS+alD)), z accumulated per-lane.
// Phase 2: weighted bf16 row gather, unrolled x4.
// Epilogue: single z wave-reduce, bias (+elu+residual bf16) + in-wave LN.
// ---------------------------------------------------------------------------
template <int H, int FINAL>
__launch_bounds__(256)
__global__ void gat_aggregate(const ushort_t* __restrict__ hWb,
                              const float* __restrict__ alS,
                              const float* __restrict__ alD,
                              const int* __restrict__ rowp,
                              const int* __restrict__ csrc,
                              const float* __restrict__ bias,
                              const ushort_t* __restrict__ resb,
                              ushort_t* __restrict__ outb,
                              float* __restrict__ outf, int n) {
    __shared__ float pbuf[4][64][4];
    __shared__ int sbuf[4][64];
    int wid = threadIdx.x >> 6;
    int lane = threadIdx.x & 63;
    int node = blockIdx.x * 4 + wid;
    if (node >= n) return;
    int c0 = lane * 2;
    float ald[4];
    if (H == 4) {
        float4 t = *(const float4*)(alD + (size_t)node * 4);
        ald[0] = t.x; ald[1] = t.y; ald[2] = t.z; ald[3] = t.w;
    } else {
        ald[0] = alD[node];
    }
    int beg = rowp[node], end = rowp[node + 1];
    float zp0 = 0.f, zp1 = 0.f, zp2 = 0.f, zp3 = 0.f;
    float a0 = 0.f, a1 = 0.f;
    int head4 = (H == 4) ? (lane >> 4) : 0;

    for (int base = beg; base < end; base += 64) {
        int nc = min(64, end - base);
        if (lane < nc) {
            int s = csrc[base + lane];
            sbuf[wid][lane] = s;
            if (H == 4) {
                float4 t = *(const float4*)(alS + (size_t)s * 4);
                float x0 = t.x + ald[0], x1 = t.y + ald[1];
                float x2 = t.z + ald[2], x3 = t.w + ald[3];
                x0 = (x0 > 0.f) ? x0 : 0.2f * x0;
                x1 = (x1 > 0.f) ? x1 : 0.2f * x1;
                x2 = (x2 > 0.f) ? x2 : 0.2f * x2;
                x3 = (x3 > 0.f) ? x3 : 0.2f * x3;
                float p0 = __expf(x0), p1 = __expf(x1);
                float p2 = __expf(x2), p3 = __expf(x3);
                zp0 += p0; zp1 += p1; zp2 += p2; zp3 += p3;
                float4 t4; t4.x = p0; t4.y = p1; t4.z = p2; t4.w = p3;
                *(float4*)&pbuf[wid][lane][0] = t4;
            } else {
                float x = alS[s] + ald[0];
                x = (x > 0.f) ? x : 0.2f * x;
                float p = __expf(x);
                zp0 += p;
                pbuf[wid][lane][0] = p;
            }
        }
        int i = 0;
        for (; i + 4 <= nc; i += 4) {
            int s0 = sbuf[wid][i], s1 = sbuf[wid][i + 1];
            int s2 = sbuf[wid][i + 2], s3 = sbuf[wid][i + 3];
            float p0 = pbuf[wid][i][head4], p1 = pbuf[wid][i + 1][head4];
            float p2 = pbuf[wid][i + 2][head4], p3 = pbuf[wid][i + 3][head4];
            uint_t h0 = ((const uint_t*)(hWb + ((size_t)s0 << 7)))[lane];
            uint_t h1 = ((const uint_t*)(hWb + ((size_t)s1 << 7)))[lane];
            uint_t h2 = ((const uint_t*)(hWb + ((size_t)s2 << 7)))[lane];
            uint_t h3 = ((const uint_t*)(hWb + ((size_t)s3 << 7)))[lane];
            a0 += p0 * bf2f_lo(h0); a1 += p0 * bf2f_hi(h0);
            a0 += p1 * bf2f_lo(h1); a1 += p1 * bf2f_hi(h1);
            a0 += p2 * bf2f_lo(h2); a1 += p2 * bf2f_hi(h2);
            a0 += p3 * bf2f_lo(h3); a1 += p3 * bf2f_hi(h3);
        }
        for (; i < nc; ++i) {
            int s0 = sbuf[wid][i];
            float p0 = pbuf[wid][i][head4];
            uint_t h0 = ((const uint_t*)(hWb + ((size_t)s0 << 7)))[lane];
            a0 += p0 * bf2f_lo(h0);
            a1 += p0 * bf2f_hi(h0);
        }
    }

#pragma unroll
    for (int off = 1; off < 64; off <<= 1) {
        zp0 += __shfl_xor(zp0, off, 64);
        if (H == 4) {
            zp1 += __shfl_xor(zp1, off, 64);
            zp2 += __shfl_xor(zp2, off, 64);
            zp3 += __shfl_xor(zp3, off, 64);
        }
    }
    float zv;
    if (H == 1) zv = zp0;
    else zv = (lane & 32) ? ((lane & 16) ? zp3 : zp2)
                          : ((lane & 16) ? zp1 : zp0);
    float inv = 1.f / (zv + 1e-16f);
    float v0 = a0 * inv + bias[c0];
    float v1 = a1 * inv + bias[c0 + 1];
    if (!FINAL) {
        uint_t rv = ((const uint_t*)(resb + ((size_t)node << 7)))[lane];
        v0 = ((v0 > 0.f) ? v0 : expm1f(v0)) + bf2f_lo(rv);
        v1 = ((v1 > 0.f) ? v1 : expm1f(v1)) + bf2f_hi(rv);
    }
    float s2 = v0 + v1;
#pragma unroll
    for (int off = 1; off < 64; off <<= 1) s2 += __shfl_xor(s2, off, 64);
    float mean = s2 * (1.f / 128.f);
    float d0 = v0 - mean, d1 = v1 - mean;
    float q = d0 * d0 + d1 * d1;
#pragma unroll
    for (int off = 1; off < 64; off <<= 1) q += __shfl_xor(q, off, 64);
    float r = rsqrtf(q * (1.f / 128.f) + 1e-5f);
    d0 *= r;
    d1 *= r;
    if (FINAL) {
        float2 o; o.x = d0; o.y = d1;
        *(float2*)(outf + ((size_t)node << 7) + c0) = o;
    } else {
        uint_t pk = (uint_t)f2bf(d0) | ((uint_t)f2bf(d1) << 16);
        ((uint_t*)(outb + ((size_t)node << 7)))[lane] = pk;
    }
}

// ---------------------------------------------------------------------------
extern "C" void kernel_launch(void* const* d_in, const int* in_sizes, int n_in,
                              void* d_out, int out_size, void* d_ws, size_t ws_size,
                              hipStream_t stream) {
    const int N = in_sizes[0] / 128;
    const int E = in_sizes[1] / 2;
    const int Etot = E + N;

    const float* x    = (const float*)d_in[0];
    const int*   ei   = (const int*)d_in[1];
    const float* W_in = (const float*)d_in[2];
    const float* b_in = (const float*)d_in[3];
    const float* W0   = (const float*)d_in[4];
    const float* as0  = (const float*)d_in[5];
    const float* ad0  = (const float*)d_in[6];
    const float* b0   = (const float*)d_in[7];
    const float* W1   = (const float*)d_in[8];
    const float* as1  = (const float*)d_in[9];
    const float* ad1  = (const float*)d_in[10];
    const float* b1   = (const float*)d_in[11];
    const float* W2   = (const float*)d_in[12];
    const float* as2  = (const float*)d_in[13];
    const float* ad2  = (const float*)d_in[14];
    const float* b2   = (const float*)d_in[15];

    char* wsp = (char*)d_ws;
    size_t off = 0;
    auto carve = [&](size_t bytes) -> void* {
        void* p = wsp + off;
        off += (bytes + 255) & ~(size_t)255;
        return p;
    };
    ushort_t* hAb  = (ushort_t*)carve((size_t)N * 128 * 2);
    ushort_t* hBb  = (ushort_t*)carve((size_t)N * 128 * 2);
    ushort_t* hWb  = (ushort_t*)carve((size_t)N * 128 * 2);
    float*    alS  = (float*)carve((size_t)N * 4 * 4);
    float*    alD  = (float*)carve((size_t)N * 4 * 4);
    int*      cnt  = (int*)carve((size_t)2 * N * 4);
    int*      cur  = cnt + N;
    int*      rowp = (int*)carve((size_t)(N + 1) * 4);
    int*      csrc = (int*)carve((size_t)Etot * 4);
    int*      part = (int*)carve((size_t)1024 * 4);
    ushort_t* BfIn = (ushort_t*)carve((size_t)4 * 8 * 64 * 8 * 2);
    ushort_t* Bf0  = (ushort_t*)carve((size_t)4 * 9 * 64 * 8 * 2);
    ushort_t* Bf1  = (ushort_t*)carve((size_t)4 * 9 * 64 * 8 * 2);
    ushort_t* Bf2  = (ushort_t*)carve((size_t)4 * 9 * 64 * 8 * 2);
    (void)ws_size; (void)n_in; (void)out_size;

    const int nb = (N + SCH - 1) / SCH;
    const int nb2 = (N + 1 + SCH - 1) / SCH;

    // B-fragment packing (independent, cheap)
    build_bfrag<0><<<1, 256, 0, stream>>>(W_in, nullptr, nullptr, BfIn);
    build_bfrag<4><<<1, 256, 0, stream>>>(W0, as0, ad0, Bf0);
    build_bfrag<4><<<1, 256, 0, stream>>>(W1, as1, ad1, Bf1);
    build_bfrag<1><<<1, 256, 0, stream>>>(W2, as2, ad2, Bf2);

    // CSR
    hipMemsetAsync(cnt, 0, (size_t)2 * N * 4, stream);
    count_kernel<<<(Etot + 255) / 256, 256, 0, stream>>>(ei, cnt, E, N);
    scan_part<<<nb, 256, 0, stream>>>(cnt, part, N);
    scan_aux<<<1, 256, 0, stream>>>(part, nb);
    scan_apply<<<nb2, 256, 0, stream>>>(cnt, part, rowp, N);
    fill_kernel<<<(Etot + 255) / 256, 256, 0, stream>>>(ei, rowp, cur, csrc, E, N);

    int gg = (N / 16 + 3) / 4;  // N = 50000 = 16*3125, one 16-row tile per wave
    int ga = (N + 3) / 4;

    // h = relu(x @ W_in + b_in) -> bf16
    gemm_mfma<0><<<gg, 256, 0, stream>>>(x, nullptr, BfIn, b_in, hAb,
                                         nullptr, nullptr, N);
    // Layer 0
    gemm_mfma<1><<<gg, 256, 0, stream>>>(nullptr, hAb, Bf0, nullptr, hWb, alS, alD, N);
    gat_aggregate<4, 0><<<ga, 256, 0, stream>>>(hWb, alS, alD, rowp, csrc, b0,
                                                hAb, hBb, nullptr, N);
    // Layer 1
    gemm_mfma<1><<<gg, 256, 0, stream>>>(nullptr, hBb, Bf1, nullptr, hWb, alS, alD, N);
    gat_aggregate<4, 0><<<ga, 256, 0, stream>>>(hWb, alS, alD, rowp, csrc, b1,
                                                hBb, hAb, nullptr, N);
    // Layer 2 (heads=1)
    gemm_mfma<2><<<gg, 256, 0, stream>>>(nullptr, hAb, Bf2, nullptr, hWb, alS, alD, N);
    gat_aggregate<1, 1><<<ga, 256, 0, stream>>>(hWb, alS, alD, rowp, csrc, b2,
                                                nullptr, nullptr, (float*)d_out, N);
}

// Round 4
// 307.479 us; speedup vs baseline: 2.0634x; 1.1163x over previous
//
#include <hip/hip_runtime.h>
#include <hip/hip_bf16.h>

typedef unsigned short ushort_t;
typedef unsigned int uint_t;
typedef __attribute__((ext_vector_type(8))) short short8;
typedef __attribute__((ext_vector_type(4))) float f32x4;

__device__ __forceinline__ ushort_t f2bf(float f) {
    uint_t u = __float_as_uint(f);
    uint_t r = (u + 0x7FFFu + ((u >> 16) & 1u)) >> 16;
    return (ushort_t)r;
}
__device__ __forceinline__ float bf2f_lo(uint_t u) { return __uint_as_float(u << 16); }
__device__ __forceinline__ float bf2f_hi(uint_t u) { return __uint_as_float(u & 0xffff0000u); }

// ---------------------------------------------------------------------------
// Bucketed CSR build. Buckets of 256 dst nodes (NB = ceil(N/256)).
// ---------------------------------------------------------------------------
#define BSH 8
#define BCK 256
#define CSR_CAP 6144

__global__ void bucket_count(const int* __restrict__ ei, int* __restrict__ gcnt,
                             int E, int N, int NB) {
    __shared__ int hist[256];
    int tid = threadIdx.x;
    hist[tid] = 0;
    __syncthreads();
    int base = blockIdx.x * 1024;
    int Etot = E + N;
#pragma unroll
    for (int r = 0; r < 4; ++r) {
        int i = base + r * 256 + tid;
        if (i < Etot) {
            int dst = (i < E) ? ei[E + i] : (i - E);
            atomicAdd(&hist[dst >> BSH], 1);
        }
    }
    __syncthreads();
    if (tid < NB && hist[tid]) atomicAdd(&gcnt[tid], hist[tid]);
}

__global__ void bucket_base(const int* __restrict__ gcnt, int* __restrict__ gbase,
                            int* __restrict__ gcur, int* __restrict__ rowp,
                            int NB, int N, int Etot) {
    __shared__ int ws[4];
    int t = threadIdx.x, lane = t & 63, w = t >> 6;
    int v = (t < NB) ? gcnt[t] : 0;
    int x = v;
#pragma unroll
    for (int off = 1; off < 64; off <<= 1) {
        int t2 = __shfl_up(x, off, 64);
        if (lane >= off) x += t2;
    }
    if (lane == 63) ws[w] = x;
    __syncthreads();
    int add = 0;
    for (int j = 0; j < w; ++j) add += ws[j];
    int excl = add + x - v;
    if (t < NB) {
        gbase[t] = excl;
        gcur[t] = excl;
    }
    if (t == 0) {
        gbase[NB] = Etot;
        rowp[N] = Etot;
    }
}

__global__ void bucket_scatter(const int* __restrict__ ei, int* __restrict__ gcur,
                               uint2* __restrict__ pairs, int E, int N, int NB) {
    __shared__ int hist[256];
    __shared__ int bbase[256];
    __shared__ int cur[256];
    int tid = threadIdx.x;
    hist[tid] = 0;
    __syncthreads();
    int base = blockIdx.x * 1024;
    int Etot = E + N;
    int srcv[4], dstv[4], bk[4];
    bool val[4];
#pragma unroll
    for (int r = 0; r < 4; ++r) {
        int i = base + r * 256 + tid;
        val[r] = (i < Etot);
        if (val[r]) {
            srcv[r] = (i < E) ? ei[i] : (i - E);
            dstv[r] = (i < E) ? ei[E + i] : (i - E);
            bk[r] = dstv[r] >> BSH;
            atomicAdd(&hist[bk[r]], 1);
        }
    }
    __syncthreads();
    if (tid < NB && hist[tid]) bbase[tid] = atomicAdd(&gcur[tid], hist[tid]);
    cur[tid] = 0;
    __syncthreads();
#pragma unroll
    for (int r = 0; r < 4; ++r) {
        if (val[r]) {
            int pos = bbase[bk[r]] + atomicAdd(&cur[bk[r]], 1);
            uint2 p;
            p.x = (uint_t)srcv[r];
            p.y = (uint_t)dstv[r];
            pairs[pos] = p;
        }
    }
}

__global__ void bucket_csr(const uint2* __restrict__ pairs, const int* __restrict__ gbase,
                           int* __restrict__ rowp, int* __restrict__ csrc, int N) {
    __shared__ int cnt[256];
    __shared__ int ws[4];
    __shared__ int stage[CSR_CAP];
    int b = blockIdx.x, tid = threadIdx.x;
    int eBeg = gbase[b], eEnd = gbase[b + 1];
    int M = eEnd - eBeg;
    cnt[tid] = 0;
    __syncthreads();
    for (int t = tid; t < M; t += 256) {
        uint2 pr = pairs[eBeg + t];
        atomicAdd(&cnt[pr.y & (BCK - 1)], 1);
    }
    __syncthreads();
    int v = cnt[tid];
    int lane = tid & 63, w = tid >> 6;
    int x = v;
#pragma unroll
    for (int off = 1; off < 64; off <<= 1) {
        int t2 = __shfl_up(x, off, 64);
        if (lane >= off) x += t2;
    }
    if (lane == 63) ws[w] = x;
    __syncthreads();
    int add = 0;
    for (int j = 0; j < w; ++j) add += ws[j];
    int excl = add + x - v;
    int node = (b << BSH) + tid;
    if (node < N) rowp[node] = eBeg + excl;
    __syncthreads();
    cnt[tid] = excl;
    __syncthreads();
    for (int t = tid; t < M; t += 256) {
        uint2 pr = pairs[eBeg + t];
        int pos = atomicAdd(&cnt[pr.y & (BCK - 1)], 1);
        if (pos < CSR_CAP) stage[pos] = (int)pr.x;
        else csrc[eBeg + pos] = (int)pr.x;
    }
    __syncthreads();
    int lim = (M < CSR_CAP) ? M : CSR_CAP;
    for (int t = tid; t < lim; t += 256) csrc[eBeg + t] = stage[t];
}

// ---------------------------------------------------------------------------
// Pre-pack B fragments in MFMA layout: [kstep(4)][ntile(NT)][lane(64)][8 bf16]
// grid = NT blocks. ntile 8 (H>0) = attention logit columns.
// ---------------------------------------------------------------------------
template <int H>
__global__ void build_bfrag(const float* __restrict__ W, const float* __restrict__ a_s,
                            const float* __restrict__ a_d, ushort_t* __restrict__ Bf) {
    const int NT = (H > 0) ? 9 : 8;
    int nt = blockIdx.x;
    int l = threadIdx.x & 63;
    int ks = threadIdx.x >> 6;
    int kb = ks * 32 + (l >> 4) * 8;
    int col = l & 15;
    ushort_t v[8];
    if (nt < 8) {
#pragma unroll
        for (int j = 0; j < 8; ++j)
            v[j] = f2bf(W[(size_t)(kb + j) * 128 + nt * 16 + col]);
    } else {
#pragma unroll
        for (int j = 0; j < 8; ++j) {
            int k = kb + j;
            float s = 0.f;
            if (H == 4) {
                if (col < 4) {
                    for (int c = 0; c < 32; ++c)
                        s += W[(size_t)k * 128 + col * 32 + c] * a_s[col * 32 + c];
                } else if (col < 8) {
                    int h = col - 4;
                    for (int c = 0; c < 32; ++c)
                        s += W[(size_t)k * 128 + h * 32 + c] * a_d[h * 32 + c];
                }
            } else {
                if (col == 0) {
                    for (int c = 0; c < 128; ++c) s += W[(size_t)k * 128 + c] * a_s[c];
                } else if (col == 1) {
                    for (int c = 0; c < 128; ++c) s += W[(size_t)k * 128 + c] * a_d[c];
                }
            }
            v[j] = f2bf(s);
        }
    }
    uint4 u;
    u.x = (uint_t)v[0] | ((uint_t)v[1] << 16);
    u.y = (uint_t)v[2] | ((uint_t)v[3] << 16);
    u.z = (uint_t)v[4] | ((uint_t)v[5] << 16);
    u.w = (uint_t)v[6] | ((uint_t)v[7] << 16);
    *(uint4*)(Bf + ((size_t)(ks * NT + nt) * 64 + l) * 8) = u;
}

// ---------------------------------------------------------------------------
// MFMA GEMM: one 16-row tile per wave, K=128, N-tiles = 8 (+1 logit tile).
// ---------------------------------------------------------------------------
template <int MODE>
__launch_bounds__(256)
__global__ void gemm_mfma(const float* __restrict__ Af, const ushort_t* __restrict__ Ab,
                          const ushort_t* __restrict__ Bf, const float* __restrict__ bias,
                          ushort_t* __restrict__ outB, float* __restrict__ alS,
                          float* __restrict__ alD, int M) {
    const int NT = (MODE == 0) ? 8 : 9;
    int wid = threadIdx.x >> 6, l = threadIdx.x & 63;
    int t = blockIdx.x * 4 + wid;
    int r0 = t * 16;
    if (r0 >= M) return;
    int lg = l >> 4, lc = l & 15;
    f32x4 acc[9];
#pragma unroll
    for (int nt = 0; nt < NT; ++nt) acc[nt] = (f32x4){0.f, 0.f, 0.f, 0.f};

#pragma unroll
    for (int ks = 0; ks < 4; ++ks) {
        int k0 = ks * 32 + lg * 8;
        short8 af;
        if (MODE == 0) {
            const float* ap = Af + (size_t)(r0 + lc) * 128 + k0;
            float4 x0 = *(const float4*)ap;
            float4 x1 = *(const float4*)(ap + 4);
            af[0] = (short)f2bf(x0.x);
            af[1] = (short)f2bf(x0.y);
            af[2] = (short)f2bf(x0.z);
            af[3] = (short)f2bf(x0.w);
            af[4] = (short)f2bf(x1.x);
            af[5] = (short)f2bf(x1.y);
            af[6] = (short)f2bf(x1.z);
            af[7] = (short)f2bf(x1.w);
        } else {
            af = *(const short8*)(Ab + (size_t)(r0 + lc) * 128 + k0);
        }
#pragma unroll
        for (int nt = 0; nt < NT; ++nt) {
            short8 bfr = *(const short8*)(Bf + ((size_t)(ks * NT + nt) * 64 + l) * 8);
            acc[nt] = __builtin_amdgcn_mfma_f32_16x16x32_bf16(af, bfr, acc[nt], 0, 0, 0);
        }
    }

    if (MODE == 0) {
        float bv[8];
#pragma unroll
        for (int nt = 0; nt < 8; ++nt) bv[nt] = bias[nt * 16 + lc];
#pragma unroll
        for (int r = 0; r < 4; ++r) {
            int row = r0 + lg * 4 + r;
            ushort_t* op = outB + (size_t)row * 128 + lc;
#pragma unroll
            for (int nt = 0; nt < 8; ++nt) {
                float v = fmaxf(acc[nt][r] + bv[nt], 0.f);
                op[nt * 16] = f2bf(v);
            }
        }
    } else {
#pragma unroll
        for (int r = 0; r < 4; ++r) {
            int row = r0 + lg * 4 + r;
            ushort_t* op = outB + (size_t)row * 128 + lc;
#pragma unroll
            for (int nt = 0; nt < 8; ++nt) op[nt * 16] = f2bf(acc[nt][r]);
            float lv = acc[8][r];
            if (MODE == 1) {
                if (lc < 4) alS[(size_t)row * 4 + lc] = lv;
                else if (lc < 8) alD[(size_t)row * 4 + (lc - 4)] = lv;
            } else {
                if (lc == 0) alS[row] = lv;
                else if (lc == 1) alD[row] = lv;
            }
        }
    }
}

// ---------------------------------------------------------------------------
// Fused GAT aggregation.
// Phase 1: lanes own edges; p = exp(leaky(alS+alD)) per head, z per-lane.
// Phase 2: 16-lane groups each gather a DIFFERENT edge's row as uint4 (16B):
//          4 edges per load instruction; per-lane 8-channel f32 accumulators.
// Combine groups via shfl_xor(16,32); epilogue (bias/elu/res/LN) in j-layout.
// ---------------------------------------------------------------------------
template <int H, int FINAL>
__launch_bounds__(256)
__global__ void gat_aggregate(const ushort_t* __restrict__ hWb,
                              const float* __restrict__ alS,
                              const float* __restrict__ alD,
                              const int* __restrict__ rowp,
                              const int* __restrict__ csrc,
                              const float* __restrict__ bias,
                              const ushort_t* __restrict__ resb,
                              ushort_t* __restrict__ outb,
                              float* __restrict__ outf, int n) {
    __shared__ float pbuf[4][64][4];
    __shared__ int sbuf[4][64];
    int wid = threadIdx.x >> 6;
    int lane = threadIdx.x & 63;
    int node = blockIdx.x * 4 + wid;
    if (node >= n) return;
    int g = lane >> 4;
    int j = lane & 15;
    int hsel = (H == 4) ? (j >> 2) : 0;
    float ald[4];
    if (H == 4) {
        float4 t = *(const float4*)(alD + (size_t)node * 4);
        ald[0] = t.x; ald[1] = t.y; ald[2] = t.z; ald[3] = t.w;
    } else {
        ald[0] = alD[node];
    }
    int beg = rowp[node], end = rowp[node + 1];
    float zp0 = 0.f, zp1 = 0.f, zp2 = 0.f, zp3 = 0.f;
    float acc[8];
#pragma unroll
    for (int c = 0; c < 8; ++c) acc[c] = 0.f;

    for (int base = beg; base < end; base += 64) {
        int nc = min(64, end - base);
        if (lane < nc) {
            int s = csrc[base + lane];
            sbuf[wid][lane] = s;
            if (H == 4) {
                float4 t = *(const float4*)(alS + (size_t)s * 4);
                float x0 = t.x + ald[0], x1 = t.y + ald[1];
                float x2 = t.z + ald[2], x3 = t.w + ald[3];
                x0 = (x0 > 0.f) ? x0 : 0.2f * x0;
                x1 = (x1 > 0.f) ? x1 : 0.2f * x1;
                x2 = (x2 > 0.f) ? x2 : 0.2f * x2;
                x3 = (x3 > 0.f) ? x3 : 0.2f * x3;
                float p0 = __expf(x0), p1 = __expf(x1);
                float p2 = __expf(x2), p3 = __expf(x3);
                zp0 += p0; zp1 += p1; zp2 += p2; zp3 += p3;
                float4 t4; t4.x = p0; t4.y = p1; t4.z = p2; t4.w = p3;
                *(float4*)&pbuf[wid][lane][0] = t4;
            } else {
                float x = alS[s] + ald[0];
                x = (x > 0.f) ? x : 0.2f * x;
                float p = __expf(x);
                zp0 += p;
                pbuf[wid][lane][0] = p;
            }
        }
        // phase 2: groups of 16 lanes gather 4 edges per iteration
        for (int i = 0; i < nc; i += 4) {
            int idx = i + g;
            bool vld = idx < nc;
            int ii = vld ? idx : 0;
            int s0 = sbuf[wid][ii];
            float p = vld ? pbuf[wid][ii][hsel] : 0.f;
            uint4 hv = *((const uint4*)(hWb + ((size_t)s0 << 7)) + j);
            acc[0] += p * bf2f_lo(hv.x); acc[1] += p * bf2f_hi(hv.x);
            acc[2] += p * bf2f_lo(hv.y); acc[3] += p * bf2f_hi(hv.y);
            acc[4] += p * bf2f_lo(hv.z); acc[5] += p * bf2f_hi(hv.z);
            acc[6] += p * bf2f_lo(hv.w); acc[7] += p * bf2f_hi(hv.w);
        }
    }

    // combine the 4 edge-groups (lanes with equal j end up identical)
#pragma unroll
    for (int c = 0; c < 8; ++c) {
        acc[c] += __shfl_xor(acc[c], 16, 64);
        acc[c] += __shfl_xor(acc[c], 32, 64);
    }
    // z reduce across all 64 lanes
#pragma unroll
    for (int off = 1; off < 64; off <<= 1) {
        zp0 += __shfl_xor(zp0, off, 64);
        if (H == 4) {
            zp1 += __shfl_xor(zp1, off, 64);
            zp2 += __shfl_xor(zp2, off, 64);
            zp3 += __shfl_xor(zp3, off, 64);
        }
    }
    float zv;
    if (H == 1) zv = zp0;
    else zv = (hsel == 0) ? zp0 : (hsel == 1) ? zp1 : (hsel == 2) ? zp2 : zp3;
    float inv = 1.f / (zv + 1e-16f);

    int c0 = j * 8;
    const float4* bp = (const float4*)(bias + c0);
    float4 bv0 = bp[0], bv1 = bp[1];
    float val[8];
    val[0] = acc[0] * inv + bv0.x; val[1] = acc[1] * inv + bv0.y;
    val[2] = acc[2] * inv + bv0.z; val[3] = acc[3] * inv + bv0.w;
    val[4] = acc[4] * inv + bv1.x; val[5] = acc[5] * inv + bv1.y;
    val[6] = acc[6] * inv + bv1.z; val[7] = acc[7] * inv + bv1.w;
    if (!FINAL) {
        uint4 rv = *((const uint4*)(resb + ((size_t)node << 7)) + j);
        float rr[8] = {bf2f_lo(rv.x), bf2f_hi(rv.x), bf2f_lo(rv.y), bf2f_hi(rv.y),
                       bf2f_lo(rv.z), bf2f_hi(rv.z), bf2f_lo(rv.w), bf2f_hi(rv.w)};
#pragma unroll
        for (int c = 0; c < 8; ++c) {
            float vv = val[c];
            val[c] = ((vv > 0.f) ? vv : expm1f(vv)) + rr[c];
        }
    }
    float s2 = 0.f;
#pragma unroll
    for (int c = 0; c < 8; ++c) s2 += val[c];
#pragma unroll
    for (int off = 1; off < 16; off <<= 1) s2 += __shfl_xor(s2, off, 64);
    float mean = s2 * (1.f / 128.f);
    float q = 0.f;
    float dd[8];
#pragma unroll
    for (int c = 0; c < 8; ++c) {
        dd[c] = val[c] - mean;
        q += dd[c] * dd[c];
    }
#pragma unroll
    for (int off = 1; off < 16; off <<= 1) q += __shfl_xor(q, off, 64);
    float r = rsqrtf(q * (1.f / 128.f) + 1e-5f);
    if (g == 0) {
        if (FINAL) {
            float* op = outf + ((size_t)node << 7) + c0;
            *(float4*)op = make_float4(dd[0] * r, dd[1] * r, dd[2] * r, dd[3] * r);
            *(float4*)(op + 4) = make_float4(dd[4] * r, dd[5] * r, dd[6] * r, dd[7] * r);
        } else {
            uint4 u;
            u.x = (uint_t)f2bf(dd[0] * r) | ((uint_t)f2bf(dd[1] * r) << 16);
            u.y = (uint_t)f2bf(dd[2] * r) | ((uint_t)f2bf(dd[3] * r) << 16);
            u.z = (uint_t)f2bf(dd[4] * r) | ((uint_t)f2bf(dd[5] * r) << 16);
            u.w = (uint_t)f2bf(dd[6] * r) | ((uint_t)f2bf(dd[7] * r) << 16);
            *((uint4*)(outb + ((size_t)node << 7)) + j) = u;
        }
    }
}

// ---------------------------------------------------------------------------
extern "C" void kernel_launch(void* const* d_in, const int* in_sizes, int n_in,
                              void* d_out, int out_size, void* d_ws, size_t ws_size,
                              hipStream_t stream) {
    const int N = in_sizes[0] / 128;
    const int E = in_sizes[1] / 2;
    const int Etot = E + N;
    const int NB = (N + BCK - 1) / BCK;

    const float* x    = (const float*)d_in[0];
    const int*   ei   = (const int*)d_in[1];
    const float* W_in = (const float*)d_in[2];
    const float* b_in = (const float*)d_in[3];
    const float* W0   = (const float*)d_in[4];
    const float* as0  = (const float*)d_in[5];
    const float* ad0  = (const float*)d_in[6];
    const float* b0   = (const float*)d_in[7];
    const float* W1   = (const float*)d_in[8];
    const float* as1  = (const float*)d_in[9];
    const float* ad1  = (const float*)d_in[10];
    const float* b1   = (const float*)d_in[11];
    const float* W2   = (const float*)d_in[12];
    const float* as2  = (const float*)d_in[13];
    const float* ad2  = (const float*)d_in[14];
    const float* b2   = (const float*)d_in[15];

    char* wsp = (char*)d_ws;
    size_t off = 0;
    auto carve = [&](size_t bytes) -> void* {
        void* p = wsp + off;
        off += (bytes + 255) & ~(size_t)255;
        return p;
    };
    ushort_t* hAb  = (ushort_t*)carve((size_t)N * 128 * 2);
    ushort_t* hBb  = (ushort_t*)carve((size_t)N * 128 * 2);
    ushort_t* hWb  = (ushort_t*)carve((size_t)N * 128 * 2);
    float*    alS  = (float*)carve((size_t)N * 4 * 4);
    float*    alD  = (float*)carve((size_t)N * 4 * 4);
    int*      rowp = (int*)carve((size_t)(N + 1) * 4);
    int*      csrc = (int*)carve((size_t)Etot * 4);
    int*      gcnt = (int*)carve((size_t)256 * 4);
    int*      gbase= (int*)carve((size_t)257 * 4);
    int*      gcur = (int*)carve((size_t)256 * 4);
    ushort_t* BfIn = (ushort_t*)carve((size_t)4 * 8 * 64 * 8 * 2);
    ushort_t* Bf0  = (ushort_t*)carve((size_t)4 * 9 * 64 * 8 * 2);
    ushort_t* Bf1  = (ushort_t*)carve((size_t)4 * 9 * 64 * 8 * 2);
    ushort_t* Bf2  = (ushort_t*)carve((size_t)4 * 9 * 64 * 8 * 2);
    // pairs aliases hWb: lifetime ends (bucket_csr) before hWb is written (gemm<1>)
    uint2*    pairs = (uint2*)hWb;
    (void)ws_size; (void)n_in; (void)out_size;

    // B-fragment packing (parallel over tiles)
    build_bfrag<0><<<8, 256, 0, stream>>>(W_in, nullptr, nullptr, BfIn);
    build_bfrag<4><<<9, 256, 0, stream>>>(W0, as0, ad0, Bf0);
    build_bfrag<4><<<9, 256, 0, stream>>>(W1, as1, ad1, Bf1);
    build_bfrag<1><<<9, 256, 0, stream>>>(W2, as2, ad2, Bf2);

    // Bucketed CSR build
    hipMemsetAsync(gcnt, 0, 256 * 4, stream);
    int gsc = (Etot + 1023) / 1024;
    bucket_count<<<gsc, 256, 0, stream>>>(ei, gcnt, E, N, NB);
    bucket_base<<<1, 256, 0, stream>>>(gcnt, gbase, gcur, rowp, NB, N, Etot);
    bucket_scatter<<<gsc, 256, 0, stream>>>(ei, gcur, pairs, E, N, NB);
    bucket_csr<<<NB, 256, 0, stream>>>(pairs, gbase, rowp, csrc, N);

    int gg = (N / 16 + 3) / 4;
    int ga = (N + 3) / 4;

    // h = relu(x @ W_in + b_in) -> bf16
    gemm_mfma<0><<<gg, 256, 0, stream>>>(x, nullptr, BfIn, b_in, hAb,
                                         nullptr, nullptr, N);
    // Layer 0
    gemm_mfma<1><<<gg, 256, 0, stream>>>(nullptr, hAb, Bf0, nullptr, hWb, alS, alD, N);
    gat_aggregate<4, 0><<<ga, 256, 0, stream>>>(hWb, alS, alD, rowp, csrc, b0,
                                                hAb, hBb, nullptr, N);
    // Layer 1
    gemm_mfma<1><<<gg, 256, 0, stream>>>(nullptr, hBb, Bf1, nullptr, hWb, alS, alD, N);
    gat_aggregate<4, 0><<<ga, 256, 0, stream>>>(hWb, alS, alD, rowp, csrc, b1,
                                                hBb, hAb, nullptr, N);
    // Layer 2 (heads=1)
    gemm_mfma<2><<<gg, 256, 0, stream>>>(nullptr, hAb, Bf2, nullptr, hWb, alS, alD, N);
    gat_aggregate<1, 1><<<ga, 256, 0, stream>>>(hWb, alS, alD, rowp, csrc, b2,
                                                nullptr, nullptr, (float*)d_out, N);
}

// Round 6
// 291.593 us; speedup vs baseline: 2.1758x; 1.0545x over previous
//
#include <hip/hip_runtime.h>
#include <hip/hip_bf16.h>

typedef unsigned short ushort_t;
typedef unsigned int uint_t;
typedef __attribute__((ext_vector_type(8))) short short8;
typedef __attribute__((ext_vector_type(4))) float f32x4;

__device__ __forceinline__ ushort_t f2bf(float f) {
    uint_t u = __float_as_uint(f);
    uint_t r = (u + 0x7FFFu + ((u >> 16) & 1u)) >> 16;
    return (ushort_t)r;
}
__device__ __forceinline__ float bf2f_lo(uint_t u) { return __uint_as_float(u << 16); }
__device__ __forceinline__ float bf2f_hi(uint_t u) { return __uint_as_float(u & 0xffff0000u); }
// hi bf16 with low 16 bits left as extra-mantissa garbage: value of the hi
// bf16 within 2^-9 relative -- fine for the error budget, saves the AND.
__device__ __forceinline__ float bf2f_hi_fast(uint_t u) { return __uint_as_float(u); }

// ---------------------------------------------------------------------------
// Bucketed CSR build. Buckets of 256 dst nodes (NB = ceil(N/256)).
// ---------------------------------------------------------------------------
#define BSH 8
#define BCK 256
#define CSR_CAP 6144

__global__ void bucket_count(const int* __restrict__ ei, int* __restrict__ gcnt,
                             int E, int N, int NB) {
    __shared__ int hist[256];
    int tid = threadIdx.x;
    hist[tid] = 0;
    __syncthreads();
    int base = blockIdx.x * 1024;
    int Etot = E + N;
#pragma unroll
    for (int r = 0; r < 4; ++r) {
        int i = base + r * 256 + tid;
        if (i < Etot) {
            int dst = (i < E) ? ei[E + i] : (i - E);
            atomicAdd(&hist[dst >> BSH], 1);
        }
    }
    __syncthreads();
    if (tid < NB && hist[tid]) atomicAdd(&gcnt[tid], hist[tid]);
}

__global__ void bucket_base(const int* __restrict__ gcnt, int* __restrict__ gbase,
                            int* __restrict__ gcur, int* __restrict__ rowp,
                            int NB, int N, int Etot) {
    __shared__ int ws[4];
    int t = threadIdx.x, lane = t & 63, w = t >> 6;
    int v = (t < NB) ? gcnt[t] : 0;
    int x = v;
#pragma unroll
    for (int off = 1; off < 64; off <<= 1) {
        int t2 = __shfl_up(x, off, 64);
        if (lane >= off) x += t2;
    }
    if (lane == 63) ws[w] = x;
    __syncthreads();
    int add = 0;
    for (int j = 0; j < w; ++j) add += ws[j];
    int excl = add + x - v;
    if (t < NB) {
        gbase[t] = excl;
        gcur[t] = excl;
    }
    if (t == 0) {
        gbase[NB] = Etot;
        rowp[N] = Etot;
    }
}

__global__ void bucket_scatter(const int* __restrict__ ei, int* __restrict__ gcur,
                               uint2* __restrict__ pairs, int E, int N, int NB) {
    __shared__ int hist[256];
    __shared__ int bbase[256];
    __shared__ int cur[256];
    int tid = threadIdx.x;
    hist[tid] = 0;
    __syncthreads();
    int base = blockIdx.x * 1024;
    int Etot = E + N;
    int srcv[4], dstv[4], bk[4];
    bool val[4];
#pragma unroll
    for (int r = 0; r < 4; ++r) {
        int i = base + r * 256 + tid;
        val[r] = (i < Etot);
        if (val[r]) {
            srcv[r] = (i < E) ? ei[i] : (i - E);
            dstv[r] = (i < E) ? ei[E + i] : (i - E);
            bk[r] = dstv[r] >> BSH;
            atomicAdd(&hist[bk[r]], 1);
        }
    }
    __syncthreads();
    if (tid < NB && hist[tid]) bbase[tid] = atomicAdd(&gcur[tid], hist[tid]);
    cur[tid] = 0;
    __syncthreads();
#pragma unroll
    for (int r = 0; r < 4; ++r) {
        if (val[r]) {
            int pos = bbase[bk[r]] + atomicAdd(&cur[bk[r]], 1);
            uint2 p;
            p.x = (uint_t)srcv[r];
            p.y = (uint_t)dstv[r];
            pairs[pos] = p;
        }
    }
}

__global__ void bucket_csr(const uint2* __restrict__ pairs, const int* __restrict__ gbase,
                           int* __restrict__ rowp, int* __restrict__ csrc, int N) {
    __shared__ int cnt[256];
    __shared__ int ws[4];
    __shared__ int stage[CSR_CAP];
    int b = blockIdx.x, tid = threadIdx.x;
    int eBeg = gbase[b], eEnd = gbase[b + 1];
    int M = eEnd - eBeg;
    cnt[tid] = 0;
    __syncthreads();
    for (int t = tid; t < M; t += 256) {
        uint2 pr = pairs[eBeg + t];
        atomicAdd(&cnt[pr.y & (BCK - 1)], 1);
    }
    __syncthreads();
    int v = cnt[tid];
    int lane = tid & 63, w = tid >> 6;
    int x = v;
#pragma unroll
    for (int off = 1; off < 64; off <<= 1) {
        int t2 = __shfl_up(x, off, 64);
        if (lane >= off) x += t2;
    }
    if (lane == 63) ws[w] = x;
    __syncthreads();
    int add = 0;
    for (int j = 0; j < w; ++j) add += ws[j];
    int excl = add + x - v;
    int node = (b << BSH) + tid;
    if (node < N) rowp[node] = eBeg + excl;
    __syncthreads();
    cnt[tid] = excl;
    __syncthreads();
    for (int t = tid; t < M; t += 256) {
        uint2 pr = pairs[eBeg + t];
        int pos = atomicAdd(&cnt[pr.y & (BCK - 1)], 1);
        if (pos < CSR_CAP) stage[pos] = (int)pr.x;
        else csrc[eBeg + pos] = (int)pr.x;
    }
    __syncthreads();
    int lim = (M < CSR_CAP) ? M : CSR_CAP;
    for (int t = tid; t < lim; t += 256) csrc[eBeg + t] = stage[t];
}

// ---------------------------------------------------------------------------
// Pre-pack B fragments in MFMA layout: [kstep(4)][ntile(NT)][lane(64)][8 bf16]
// grid = NT blocks. ntile 8 (H>0) = attention logit columns.
// ---------------------------------------------------------------------------
template <int H>
__global__ void build_bfrag(const float* __restrict__ W, const float* __restrict__ a_s,
                            const float* __restrict__ a_d, ushort_t* __restrict__ Bf) {
    const int NT = (H > 0) ? 9 : 8;
    int nt = blockIdx.x;
    int l = threadIdx.x & 63;
    int ks = threadIdx.x >> 6;
    int kb = ks * 32 + (l >> 4) * 8;
    int col = l & 15;
    ushort_t v[8];
    if (nt < 8) {
#pragma unroll
        for (int j = 0; j < 8; ++j)
            v[j] = f2bf(W[(size_t)(kb + j) * 128 + nt * 16 + col]);
    } else {
#pragma unroll
        for (int j = 0; j < 8; ++j) {
            int k = kb + j;
            float s = 0.f;
            if (H == 4) {
                if (col < 4) {
                    for (int c = 0; c < 32; ++c)
                        s += W[(size_t)k * 128 + col * 32 + c] * a_s[col * 32 + c];
                } else if (col < 8) {
                    int h = col - 4;
                    for (int c = 0; c < 32; ++c)
                        s += W[(size_t)k * 128 + h * 32 + c] * a_d[h * 32 + c];
                }
            } else {
                if (col == 0) {
                    for (int c = 0; c < 128; ++c) s += W[(size_t)k * 128 + c] * a_s[c];
                } else if (col == 1) {
                    for (int c = 0; c < 128; ++c) s += W[(size_t)k * 128 + c] * a_d[c];
                }
            }
            v[j] = f2bf(s);
        }
    }
    uint4 u;
    u.x = (uint_t)v[0] | ((uint_t)v[1] << 16);
    u.y = (uint_t)v[2] | ((uint_t)v[3] << 16);
    u.z = (uint_t)v[4] | ((uint_t)v[5] << 16);
    u.w = (uint_t)v[6] | ((uint_t)v[7] << 16);
    *(uint4*)(Bf + ((size_t)(ks * NT + nt) * 64 + l) * 8) = u;
}

// ---------------------------------------------------------------------------
// MFMA GEMM: one 16-row tile per wave, K=128, N-tiles = 8 (+1 logit tile).
// B fragments staged once per block in LDS (shared by 4 waves).
// ---------------------------------------------------------------------------
template <int MODE>
__launch_bounds__(256)
__global__ void gemm_mfma(const float* __restrict__ Af, const ushort_t* __restrict__ Ab,
                          const ushort_t* __restrict__ Bf, const float* __restrict__ bias,
                          ushort_t* __restrict__ outB, float* __restrict__ alS,
                          float* __restrict__ alD, int M) {
    const int NT = (MODE == 0) ? 8 : 9;
    __shared__ ushort_t Bs[4 * 9 * 64 * 8];   // up to 36 KB
    {
        const int tot = 4 * NT * 64;          // uint4 slots
        for (int t = threadIdx.x; t < tot; t += 256)
            ((uint4*)Bs)[t] = ((const uint4*)Bf)[t];
    }
    __syncthreads();

    int wid = threadIdx.x >> 6, l = threadIdx.x & 63;
    int t = blockIdx.x * 4 + wid;
    int r0 = t * 16;
    if (r0 >= M) return;
    int lg = l >> 4, lc = l & 15;
    f32x4 acc[9];
#pragma unroll
    for (int nt = 0; nt < NT; ++nt) acc[nt] = (f32x4){0.f, 0.f, 0.f, 0.f};

#pragma unroll
    for (int ks = 0; ks < 4; ++ks) {
        int k0 = ks * 32 + lg * 8;
        short8 af;
        if (MODE == 0) {
            const float* ap = Af + (size_t)(r0 + lc) * 128 + k0;
            float4 x0 = *(const float4*)ap;
            float4 x1 = *(const float4*)(ap + 4);
            af[0] = (short)f2bf(x0.x);
            af[1] = (short)f2bf(x0.y);
            af[2] = (short)f2bf(x0.z);
            af[3] = (short)f2bf(x0.w);
            af[4] = (short)f2bf(x1.x);
            af[5] = (short)f2bf(x1.y);
            af[6] = (short)f2bf(x1.z);
            af[7] = (short)f2bf(x1.w);
        } else {
            af = *(const short8*)(Ab + (size_t)(r0 + lc) * 128 + k0);
        }
#pragma unroll
        for (int nt = 0; nt < NT; ++nt) {
            short8 bfr = *(const short8*)(Bs + ((size_t)(ks * NT + nt) * 64 + l) * 8);
            acc[nt] = __builtin_amdgcn_mfma_f32_16x16x32_bf16(af, bfr, acc[nt], 0, 0, 0);
        }
    }

    if (MODE == 0) {
        float bv[8];
#pragma unroll
        for (int nt = 0; nt < 8; ++nt) bv[nt] = bias[nt * 16 + lc];
#pragma unroll
        for (int r = 0; r < 4; ++r) {
            int row = r0 + lg * 4 + r;
            ushort_t* op = outB + (size_t)row * 128 + lc;
#pragma unroll
            for (int nt = 0; nt < 8; ++nt) {
                float v = fmaxf(acc[nt][r] + bv[nt], 0.f);
                op[nt * 16] = f2bf(v);
            }
        }
    } else {
#pragma unroll
        for (int r = 0; r < 4; ++r) {
            int row = r0 + lg * 4 + r;
            ushort_t* op = outB + (size_t)row * 128 + lc;
#pragma unroll
            for (int nt = 0; nt < 8; ++nt) op[nt * 16] = f2bf(acc[nt][r]);
            float lv = acc[8][r];
            if (MODE == 1) {
                if (lc < 4) alS[(size_t)row * 4 + lc] = lv;
                else if (lc < 8) alD[(size_t)row * 4 + (lc - 4)] = lv;
            } else {
                if (lc == 0) alS[row] = lv;
                else if (lc == 1) alD[row] = lv;
            }
        }
    }
}

// ---------------------------------------------------------------------------
// Fused GAT aggregation.
// Phase 1: lanes own edges; p = exp(leaky(alS+alD)) per head, z per-lane.
//          Pad lanes write (p=0, row=self) so phase 2 needs NO conditionals.
// Phase 2: 16-lane groups gather different edges' rows as uint4 (16B),
//          unrolled x2 (8 edges / iter), padded loop bound.
// Combine groups via shfl_xor(16,32); epilogue (bias/elu/res/LN) in j-layout.
// ---------------------------------------------------------------------------
template <int H, int FINAL>
__launch_bounds__(256)
__global__ void gat_aggregate(const ushort_t* __restrict__ hWb,
                              const float* __restrict__ alS,
                              const float* __restrict__ alD,
                              const int* __restrict__ rowp,
                              const int* __restrict__ csrc,
                              const float* __restrict__ bias,
                              const ushort_t* __restrict__ resb,
                              ushort_t* __restrict__ outb,
                              float* __restrict__ outf, int n) {
    __shared__ float pbuf[4][64][4];
    __shared__ int obuf[4][64];   // byte offsets of src rows
    int wid = threadIdx.x >> 6;
    int lane = threadIdx.x & 63;
    int node = blockIdx.x * 4 + wid;
    if (node >= n) return;
    int g = lane >> 4;
    int j = lane & 15;
    int hsel = (H == 4) ? (j >> 2) : 0;
    float ald[4];
    if (H == 4) {
        float4 t = *(const float4*)(alD + (size_t)node * 4);
        ald[0] = t.x; ald[1] = t.y; ald[2] = t.z; ald[3] = t.w;
    } else {
        ald[0] = alD[node];
    }
    int beg = rowp[node], end = rowp[node + 1];
    float zp0 = 0.f, zp1 = 0.f, zp2 = 0.f, zp3 = 0.f;
    float acc[8];
#pragma unroll
    for (int c = 0; c < 8; ++c) acc[c] = 0.f;
    const char* hbase = (const char*)hWb;
    int jo = j << 4;

    for (int base = beg; base < end; base += 64) {
        int nc = min(64, end - base);
        if (lane < nc) {
            int s = csrc[base + lane];
            obuf[wid][lane] = s << 8;
            if (H == 4) {
                float4 t = *(const float4*)(alS + (size_t)s * 4);
                float x0 = t.x + ald[0], x1 = t.y + ald[1];
                float x2 = t.z + ald[2], x3 = t.w + ald[3];
                x0 = (x0 > 0.f) ? x0 : 0.2f * x0;
                x1 = (x1 > 0.f) ? x1 : 0.2f * x1;
                x2 = (x2 > 0.f) ? x2 : 0.2f * x2;
                x3 = (x3 > 0.f) ? x3 : 0.2f * x3;
                float p0 = __expf(x0), p1 = __expf(x1);
                float p2 = __expf(x2), p3 = __expf(x3);
                zp0 += p0; zp1 += p1; zp2 += p2; zp3 += p3;
                float4 t4; t4.x = p0; t4.y = p1; t4.z = p2; t4.w = p3;
                *(float4*)&pbuf[wid][lane][0] = t4;
            } else {
                float x = alS[s] + ald[0];
                x = (x > 0.f) ? x : 0.2f * x;
                float p = __expf(x);
                zp0 += p;
                pbuf[wid][lane][0] = p;
            }
        } else {
            obuf[wid][lane] = node << 8;     // valid self row
            if (H == 4) {
                float4 t4; t4.x = 0.f; t4.y = 0.f; t4.z = 0.f; t4.w = 0.f;
                *(float4*)&pbuf[wid][lane][0] = t4;
            } else {
                pbuf[wid][lane][0] = 0.f;
            }
        }
        // phase 2: padded, unconditional, 8 edges per iteration
        int padded = (nc + 7) & ~7;
        for (int i = 0; i < padded; i += 8) {
            int i0 = i + g, i1 = i + 4 + g;
            int o0 = obuf[wid][i0];
            int o1 = obuf[wid][i1];
            float p0 = pbuf[wid][i0][hsel];
            float p1 = pbuf[wid][i1][hsel];
            uint4 h0 = *(const uint4*)(hbase + o0 + jo);
            uint4 h1 = *(const uint4*)(hbase + o1 + jo);
            acc[0] += p0 * bf2f_lo(h0.x); acc[1] += p0 * bf2f_hi_fast(h0.x);
            acc[2] += p0 * bf2f_lo(h0.y); acc[3] += p0 * bf2f_hi_fast(h0.y);
            acc[4] += p0 * bf2f_lo(h0.z); acc[5] += p0 * bf2f_hi_fast(h0.z);
            acc[6] += p0 * bf2f_lo(h0.w); acc[7] += p0 * bf2f_hi_fast(h0.w);
            acc[0] += p1 * bf2f_lo(h1.x); acc[1] += p1 * bf2f_hi_fast(h1.x);
            acc[2] += p1 * bf2f_lo(h1.y); acc[3] += p1 * bf2f_hi_fast(h1.y);
            acc[4] += p1 * bf2f_lo(h1.z); acc[5] += p1 * bf2f_hi_fast(h1.z);
            acc[6] += p1 * bf2f_lo(h1.w); acc[7] += p1 * bf2f_hi_fast(h1.w);
        }
    }

    // combine the 4 edge-groups (lanes with equal j end up identical)
#pragma unroll
    for (int c = 0; c < 8; ++c) {
        acc[c] += __shfl_xor(acc[c], 16, 64);
        acc[c] += __shfl_xor(acc[c], 32, 64);
    }
    // z reduce across all 64 lanes
#pragma unroll
    for (int off = 1; off < 64; off <<= 1) {
        zp0 += __shfl_xor(zp0, off, 64);
        if (H == 4) {
            zp1 += __shfl_xor(zp1, off, 64);
            zp2 += __shfl_xor(zp2, off, 64);
            zp3 += __shfl_xor(zp3, off, 64);
        }
    }
    float zv;
    if (H == 1) zv = zp0;
    else zv = (hsel == 0) ? zp0 : (hsel == 1) ? zp1 : (hsel == 2) ? zp2 : zp3;
    float inv = 1.f / (zv + 1e-16f);

    int c0 = j * 8;
    const float4* bp = (const float4*)(bias + c0);
    float4 bv0 = bp[0], bv1 = bp[1];
    float val[8];
    val[0] = acc[0] * inv + bv0.x; val[1] = acc[1] * inv + bv0.y;
    val[2] = acc[2] * inv + bv0.z; val[3] = acc[3] * inv + bv0.w;
    val[4] = acc[4] * inv + bv1.x; val[5] = acc[5] * inv + bv1.y;
    val[6] = acc[6] * inv + bv1.z; val[7] = acc[7] * inv + bv1.w;
    if (!FINAL) {
        uint4 rv = *((const uint4*)(resb + ((size_t)node << 7)) + j);
        float rr[8] = {bf2f_lo(rv.x), bf2f_hi(rv.x), bf2f_lo(rv.y), bf2f_hi(rv.y),
                       bf2f_lo(rv.z), bf2f_hi(rv.z), bf2f_lo(rv.w), bf2f_hi(rv.w)};
#pragma unroll
        for (int c = 0; c < 8; ++c) {
            float vv = val[c];
            val[c] = ((vv > 0.f) ? vv : expm1f(vv)) + rr[c];
        }
    }
    float s2 = 0.f;
#pragma unroll
    for (int c = 0; c < 8; ++c) s2 += val[c];
#pragma unroll
    for (int off = 1; off < 16; off <<= 1) s2 += __shfl_xor(s2, off, 64);
    float mean = s2 * (1.f / 128.f);
    float q = 0.f;
    float dd[8];
#pragma unroll
    for (int c = 0; c < 8; ++c) {
        dd[c] = val[c] - mean;
        q += dd[c] * dd[c];
    }
#pragma unroll
    for (int off = 1; off < 16; off <<= 1) q += __shfl_xor(q, off, 64);
    float r = rsqrtf(q * (1.f / 128.f) + 1e-5f);
    if (g == 0) {
        if (FINAL) {
            float* op = outf + ((size_t)node << 7) + c0;
            *(float4*)op = make_float4(dd[0] * r, dd[1] * r, dd[2] * r, dd[3] * r);
            *(float4*)(op + 4) = make_float4(dd[4] * r, dd[5] * r, dd[6] * r, dd[7] * r);
        } else {
            uint4 u;
            u.x = (uint_t)f2bf(dd[0] * r) | ((uint_t)f2bf(dd[1] * r) << 16);
            u.y = (uint_t)f2bf(dd[2] * r) | ((uint_t)f2bf(dd[3] * r) << 16);
            u.z = (uint_t)f2bf(dd[4] * r) | ((uint_t)f2bf(dd[5] * r) << 16);
            u.w = (uint_t)f2bf(dd[6] * r) | ((uint_t)f2bf(dd[7] * r) << 16);
            *((uint4*)(outb + ((size_t)node << 7)) + j) = u;
        }
    }
}

// ---------------------------------------------------------------------------
extern "C" void kernel_launch(void* const* d_in, const int* in_sizes, int n_in,
                              void* d_out, int out_size, void* d_ws, size_t ws_size,
                              hipStream_t stream) {
    const int N = in_sizes[0] / 128;
    const int E = in_sizes[1] / 2;
    const int Etot = E + N;
    const int NB = (N + BCK - 1) / BCK;

    const float* x    = (const float*)d_in[0];
    const int*   ei   = (const int*)d_in[1];
    const float* W_in = (const float*)d_in[2];
    const float* b_in = (const float*)d_in[3];
    const float* W0   = (const float*)d_in[4];
    const float* as0  = (const float*)d_in[5];
    const float* ad0  = (const float*)d_in[6];
    const float* b0   = (const float*)d_in[7];
    const float* W1   = (const float*)d_in[8];
    const float* as1  = (const float*)d_in[9];
    const float* ad1  = (const float*)d_in[10];
    const float* b1   = (const float*)d_in[11];
    const float* W2   = (const float*)d_in[12];
    const float* as2  = (const float*)d_in[13];
    const float* ad2  = (const float*)d_in[14];
    const float* b2   = (const float*)d_in[15];

    char* wsp = (char*)d_ws;
    size_t off = 0;
    auto carve = [&](size_t bytes) -> void* {
        void* p = wsp + off;
        off += (bytes + 255) & ~(size_t)255;
        return p;
    };
    ushort_t* hAb  = (ushort_t*)carve((size_t)N * 128 * 2);
    ushort_t* hBb  = (ushort_t*)carve((size_t)N * 128 * 2);
    ushort_t* hWb  = (ushort_t*)carve((size_t)N * 128 * 2);
    float*    alS  = (float*)carve((size_t)N * 4 * 4);
    float*    alD  = (float*)carve((size_t)N * 4 * 4);
    int*      rowp = (int*)carve((size_t)(N + 1) * 4);
    int*      csrc = (int*)carve((size_t)Etot * 4);
    int*      gcnt = (int*)carve((size_t)256 * 4);
    int*      gbase= (int*)carve((size_t)257 * 4);
    int*      gcur = (int*)carve((size_t)256 * 4);
    ushort_t* BfIn = (ushort_t*)carve((size_t)4 * 8 * 64 * 8 * 2);
    ushort_t* Bf0  = (ushort_t*)carve((size_t)4 * 9 * 64 * 8 * 2);
    ushort_t* Bf1  = (ushort_t*)carve((size_t)4 * 9 * 64 * 8 * 2);
    ushort_t* Bf2  = (ushort_t*)carve((size_t)4 * 9 * 64 * 8 * 2);
    // pairs aliases hWb: lifetime ends (bucket_csr) before hWb is written (gemm<1>)
    uint2*    pairs = (uint2*)hWb;
    (void)ws_size; (void)n_in; (void)out_size;

    // B-fragment packing (parallel over tiles)
    build_bfrag<0><<<8, 256, 0, stream>>>(W_in, nullptr, nullptr, BfIn);
    build_bfrag<4><<<9, 256, 0, stream>>>(W0, as0, ad0, Bf0);
    build_bfrag<4><<<9, 256, 0, stream>>>(W1, as1, ad1, Bf1);
    build_bfrag<1><<<9, 256, 0, stream>>>(W2, as2, ad2, Bf2);

    // Bucketed CSR build
    hipMemsetAsync(gcnt, 0, 256 * 4, stream);
    int gsc = (Etot + 1023) / 1024;
    bucket_count<<<gsc, 256, 0, stream>>>(ei, gcnt, E, N, NB);
    bucket_base<<<1, 256, 0, stream>>>(gcnt, gbase, gcur, rowp, NB, N, Etot);
    bucket_scatter<<<gsc, 256, 0, stream>>>(ei, gcur, pairs, E, N, NB);
    bucket_csr<<<NB, 256, 0, stream>>>(pairs, gbase, rowp, csrc, N);

    int gg = (N / 16 + 3) / 4;
    int ga = (N + 3) / 4;

    // h = relu(x @ W_in + b_in) -> bf16
    gemm_mfma<0><<<gg, 256, 0, stream>>>(x, nullptr, BfIn, b_in, hAb,
                                         nullptr, nullptr, N);
    // Layer 0
    gemm_mfma<1><<<gg, 256, 0, stream>>>(nullptr, hAb, Bf0, nullptr, hWb, alS, alD, N);
    gat_aggregate<4, 0><<<ga, 256, 0, stream>>>(hWb, alS, alD, rowp, csrc, b0,
                                                hAb, hBb, nullptr, N);
    // Layer 1
    gemm_mfma<1><<<gg, 256, 0, stream>>>(nullptr, hBb, Bf1, nullptr, hWb, alS, alD, N);
    gat_aggregate<4, 0><<<ga, 256, 0, stream>>>(hWb, alS, alD, rowp, csrc, b1,
                                                hBb, hAb, nullptr, N);
    // Layer 2 (heads=1)
    gemm_mfma<2><<<gg, 256, 0, stream>>>(nullptr, hAb, Bf2, nullptr, hWb, alS, alD, N);
    gat_aggregate<1, 1><<<ga, 256, 0, stream>>>(hWb, alS, alD, rowp, csrc, b2,
                                                nullptr, nullptr, (float*)d_out, N);
}

// Round 7
// 247.240 us; speedup vs baseline: 2.5661x; 1.1794x over previous
//
#include <hip/hip_runtime.h>
#include <hip/hip_bf16.h>

typedef unsigned short ushort_t;
typedef unsigned int uint_t;
typedef __attribute__((ext_vector_type(8))) short short8;
typedef __attribute__((ext_vector_type(4))) float f32x4;

__device__ __forceinline__ ushort_t f2bf(float f) {
    uint_t u = __float_as_uint(f);
    uint_t r = (u + 0x7FFFu + ((u >> 16) & 1u)) >> 16;
    return (ushort_t)r;
}
__device__ __forceinline__ float bf2f_lo(uint_t u) { return __uint_as_float(u << 16); }
__device__ __forceinline__ float bf2f_hi(uint_t u) { return __uint_as_float(u & 0xffff0000u); }
// hi bf16 with low 16 bits left as extra-mantissa garbage (<=2^-9 relative).
__device__ __forceinline__ float bf2f_hi_fast(uint_t u) { return __uint_as_float(u); }

#define BSH 8
#define BCK 256
#define CSR_CAP 6144

// ---------------------------------------------------------------------------
// prep_kernel: blocks 0..34 build the 4 B-fragment tables (MFMA layout),
// blocks 35.. do the bucket histogram for the CSR build.
// Bfrag layout: [kstep(4)][ntile(NT)][lane(64)][8 bf16]; ntile 8 = logits.
// ---------------------------------------------------------------------------
__global__ void prep_kernel(const float* __restrict__ W_in,
                            const float* __restrict__ W0, const float* __restrict__ as0,
                            const float* __restrict__ ad0,
                            const float* __restrict__ W1, const float* __restrict__ as1,
                            const float* __restrict__ ad1,
                            const float* __restrict__ W2, const float* __restrict__ as2,
                            const float* __restrict__ ad2,
                            ushort_t* __restrict__ BfIn, ushort_t* __restrict__ Bf0,
                            ushort_t* __restrict__ Bf1, ushort_t* __restrict__ Bf2,
                            const int* __restrict__ ei, int* __restrict__ gcnt,
                            int E, int N, int NB) {
    __shared__ int hist[256];
    int b = blockIdx.x;
    if (b < 35) {
        const float *W, *a_s, *a_d;
        ushort_t* Bf;
        int H, NT, nt;
        if (b < 8)       { W = W_in; a_s = nullptr; a_d = nullptr; Bf = BfIn; H = 0; NT = 8; nt = b; }
        else if (b < 17) { W = W0; a_s = as0; a_d = ad0; Bf = Bf0; H = 4; NT = 9; nt = b - 8; }
        else if (b < 26) { W = W1; a_s = as1; a_d = ad1; Bf = Bf1; H = 4; NT = 9; nt = b - 17; }
        else             { W = W2; a_s = as2; a_d = ad2; Bf = Bf2; H = 1; NT = 9; nt = b - 26; }
        int l = threadIdx.x & 63;
        int ks = threadIdx.x >> 6;
        int kb = ks * 32 + (l >> 4) * 8;
        int col = l & 15;
        ushort_t v[8];
        if (nt < 8) {
#pragma unroll
            for (int j = 0; j < 8; ++j)
                v[j] = f2bf(W[(size_t)(kb + j) * 128 + nt * 16 + col]);
        } else {
#pragma unroll
            for (int j = 0; j < 8; ++j) {
                int k = kb + j;
                float s = 0.f;
                if (H == 4) {
                    if (col < 4) {
                        for (int c = 0; c < 32; ++c)
                            s += W[(size_t)k * 128 + col * 32 + c] * a_s[col * 32 + c];
                    } else if (col < 8) {
                        int h = col - 4;
                        for (int c = 0; c < 32; ++c)
                            s += W[(size_t)k * 128 + h * 32 + c] * a_d[h * 32 + c];
                    }
                } else {
                    if (col == 0) {
                        for (int c = 0; c < 128; ++c) s += W[(size_t)k * 128 + c] * a_s[c];
                    } else if (col == 1) {
                        for (int c = 0; c < 128; ++c) s += W[(size_t)k * 128 + c] * a_d[c];
                    }
                }
                v[j] = f2bf(s);
            }
        }
        uint4 u;
        u.x = (uint_t)v[0] | ((uint_t)v[1] << 16);
        u.y = (uint_t)v[2] | ((uint_t)v[3] << 16);
        u.z = (uint_t)v[4] | ((uint_t)v[5] << 16);
        u.w = (uint_t)v[6] | ((uint_t)v[7] << 16);
        *(uint4*)(Bf + ((size_t)(ks * NT + nt) * 64 + l) * 8) = u;
    } else {
        int tid = threadIdx.x;
        hist[tid] = 0;
        __syncthreads();
        int base = (b - 35) * 1024;
        int Etot = E + N;
#pragma unroll
        for (int r = 0; r < 4; ++r) {
            int i = base + r * 256 + tid;
            if (i < Etot) {
                int dst = (i < E) ? ei[E + i] : (i - E);
                atomicAdd(&hist[dst >> BSH], 1);
            }
        }
        __syncthreads();
        if (tid < NB && hist[tid]) atomicAdd(&gcnt[tid], hist[tid]);
    }
}

__global__ void bucket_base(const int* __restrict__ gcnt, int* __restrict__ gbase,
                            int* __restrict__ gcur, int* __restrict__ rowp,
                            int NB, int N, int Etot) {
    __shared__ int ws[4];
    int t = threadIdx.x, lane = t & 63, w = t >> 6;
    int v = (t < NB) ? gcnt[t] : 0;
    int x = v;
#pragma unroll
    for (int off = 1; off < 64; off <<= 1) {
        int t2 = __shfl_up(x, off, 64);
        if (lane >= off) x += t2;
    }
    if (lane == 63) ws[w] = x;
    __syncthreads();
    int add = 0;
    for (int j = 0; j < w; ++j) add += ws[j];
    int excl = add + x - v;
    if (t < NB) {
        gbase[t] = excl;
        gcur[t] = excl;
    }
    if (t == 0) {
        gbase[NB] = Etot;
        rowp[N] = Etot;
    }
}

__global__ void bucket_scatter(const int* __restrict__ ei, int* __restrict__ gcur,
                               uint2* __restrict__ pairs, int E, int N, int NB) {
    __shared__ int hist[256];
    __shared__ int bbase[256];
    __shared__ int cur[256];
    int tid = threadIdx.x;
    hist[tid] = 0;
    __syncthreads();
    int base = blockIdx.x * 1024;
    int Etot = E + N;
    int srcv[4], dstv[4], bk[4];
    bool val[4];
#pragma unroll
    for (int r = 0; r < 4; ++r) {
        int i = base + r * 256 + tid;
        val[r] = (i < Etot);
        if (val[r]) {
            srcv[r] = (i < E) ? ei[i] : (i - E);
            dstv[r] = (i < E) ? ei[E + i] : (i - E);
            bk[r] = dstv[r] >> BSH;
            atomicAdd(&hist[bk[r]], 1);
        }
    }
    __syncthreads();
    if (tid < NB && hist[tid]) bbase[tid] = atomicAdd(&gcur[tid], hist[tid]);
    cur[tid] = 0;
    __syncthreads();
#pragma unroll
    for (int r = 0; r < 4; ++r) {
        if (val[r]) {
            int pos = bbase[bk[r]] + atomicAdd(&cur[bk[r]], 1);
            uint2 p;
            p.x = (uint_t)srcv[r];
            p.y = (uint_t)dstv[r];
            pairs[pos] = p;
        }
    }
}

__global__ void bucket_csr(const uint2* __restrict__ pairs, const int* __restrict__ gbase,
                           int* __restrict__ rowp, int* __restrict__ csrc, int N) {
    __shared__ int cnt[256];
    __shared__ int ws[4];
    __shared__ int stage[CSR_CAP];
    int b = blockIdx.x, tid = threadIdx.x;
    int eBeg = gbase[b], eEnd = gbase[b + 1];
    int M = eEnd - eBeg;
    cnt[tid] = 0;
    __syncthreads();
    for (int t = tid; t < M; t += 256) {
        uint2 pr = pairs[eBeg + t];
        atomicAdd(&cnt[pr.y & (BCK - 1)], 1);
    }
    __syncthreads();
    int v = cnt[tid];
    int lane = tid & 63, w = tid >> 6;
    int x = v;
#pragma unroll
    for (int off = 1; off < 64; off <<= 1) {
        int t2 = __shfl_up(x, off, 64);
        if (lane >= off) x += t2;
    }
    if (lane == 63) ws[w] = x;
    __syncthreads();
    int add = 0;
    for (int j = 0; j < w; ++j) add += ws[j];
    int excl = add + x - v;
    int node = (b << BSH) + tid;
    if (node < N) rowp[node] = eBeg + excl;
    __syncthreads();
    cnt[tid] = excl;
    __syncthreads();
    for (int t = tid; t < M; t += 256) {
        uint2 pr = pairs[eBeg + t];
        int pos = atomicAdd(&cnt[pr.y & (BCK - 1)], 1);
        if (pos < CSR_CAP) stage[pos] = (int)pr.x;
        else csrc[eBeg + pos] = (int)pr.x;
    }
    __syncthreads();
    int lim = (M < CSR_CAP) ? M : CSR_CAP;
    for (int t = tid; t < lim; t += 256) csrc[eBeg + t] = stage[t];
}

// ---------------------------------------------------------------------------
// MFMA GEMM: TWO 16-row tiles per wave (each B ds_read feeds 2 MFMAs).
// K=128, N-tiles = 8 (+1 logit tile). B staged in LDS per block.
// ---------------------------------------------------------------------------
template <int MODE>
__device__ __forceinline__ void gemm_epilogue(f32x4* acc, int r0, int lg, int lc,
                                              const float* bias, ushort_t* outB,
                                              float* alS, float* alD) {
    if (MODE == 0) {
#pragma unroll
        for (int r = 0; r < 4; ++r) {
            int row = r0 + lg * 4 + r;
            ushort_t* op = outB + (size_t)row * 128 + lc;
#pragma unroll
            for (int nt = 0; nt < 8; ++nt) {
                float v = fmaxf(acc[nt][r] + bias[nt * 16 + lc], 0.f);
                op[nt * 16] = f2bf(v);
            }
        }
    } else {
#pragma unroll
        for (int r = 0; r < 4; ++r) {
            int row = r0 + lg * 4 + r;
            ushort_t* op = outB + (size_t)row * 128 + lc;
#pragma unroll
            for (int nt = 0; nt < 8; ++nt) op[nt * 16] = f2bf(acc[nt][r]);
            float lv = acc[8][r];
            if (MODE == 1) {
                if (lc < 4) alS[(size_t)row * 4 + lc] = lv;
                else if (lc < 8) alD[(size_t)row * 4 + (lc - 4)] = lv;
            } else {
                if (lc == 0) alS[row] = lv;
                else if (lc == 1) alD[row] = lv;
            }
        }
    }
}

template <int MODE>
__launch_bounds__(256)
__global__ void gemm_mfma(const float* __restrict__ Af, const ushort_t* __restrict__ Ab,
                          const ushort_t* __restrict__ Bf, const float* __restrict__ bias,
                          ushort_t* __restrict__ outB, float* __restrict__ alS,
                          float* __restrict__ alD, int M) {
    const int NT = (MODE == 0) ? 8 : 9;
    __shared__ ushort_t Bs[4 * 9 * 64 * 8];   // up to 36 KB
    {
        const int tot = 4 * NT * 64;
        for (int t = threadIdx.x; t < tot; t += 256)
            ((uint4*)Bs)[t] = ((const uint4*)Bf)[t];
    }
    __syncthreads();

    int wid = threadIdx.x >> 6, l = threadIdx.x & 63;
    int lg = l >> 4, lc = l & 15;
    int r0 = (blockIdx.x * 4 + wid) * 32;
    if (r0 >= M) return;
    bool has1 = (r0 + 16) < M;
    int rowA0 = r0 + lc;
    int rowA1 = has1 ? (r0 + 16 + lc) : rowA0;

    f32x4 acc0[9], acc1[9];
#pragma unroll
    for (int nt = 0; nt < NT; ++nt) {
        acc0[nt] = (f32x4){0.f, 0.f, 0.f, 0.f};
        acc1[nt] = (f32x4){0.f, 0.f, 0.f, 0.f};
    }

#pragma unroll
    for (int ks = 0; ks < 4; ++ks) {
        int k0 = ks * 32 + lg * 8;
        short8 af0, af1;
        if (MODE == 0) {
            const float* ap0 = Af + (size_t)rowA0 * 128 + k0;
            const float* ap1 = Af + (size_t)rowA1 * 128 + k0;
            float4 x0 = *(const float4*)ap0;
            float4 x1 = *(const float4*)(ap0 + 4);
            float4 y0 = *(const float4*)ap1;
            float4 y1 = *(const float4*)(ap1 + 4);
            af0[0] = (short)f2bf(x0.x); af0[1] = (short)f2bf(x0.y);
            af0[2] = (short)f2bf(x0.z); af0[3] = (short)f2bf(x0.w);
            af0[4] = (short)f2bf(x1.x); af0[5] = (short)f2bf(x1.y);
            af0[6] = (short)f2bf(x1.z); af0[7] = (short)f2bf(x1.w);
            af1[0] = (short)f2bf(y0.x); af1[1] = (short)f2bf(y0.y);
            af1[2] = (short)f2bf(y0.z); af1[3] = (short)f2bf(y0.w);
            af1[4] = (short)f2bf(y1.x); af1[5] = (short)f2bf(y1.y);
            af1[6] = (short)f2bf(y1.z); af1[7] = (short)f2bf(y1.w);
        } else {
            af0 = *(const short8*)(Ab + (size_t)rowA0 * 128 + k0);
            af1 = *(const short8*)(Ab + (size_t)rowA1 * 128 + k0);
        }
#pragma unroll
        for (int nt = 0; nt < NT; ++nt) {
            short8 bfr = *(const short8*)(Bs + ((size_t)(ks * NT + nt) * 64 + l) * 8);
            acc0[nt] = __builtin_amdgcn_mfma_f32_16x16x32_bf16(af0, bfr, acc0[nt], 0, 0, 0);
            acc1[nt] = __builtin_amdgcn_mfma_f32_16x16x32_bf16(af1, bfr, acc1[nt], 0, 0, 0);
        }
    }

    gemm_epilogue<MODE>(acc0, r0, lg, lc, bias, outB, alS, alD);
    if (has1) gemm_epilogue<MODE>(acc1, r0 + 16, lg, lc, bias, outB, alS, alD);
}

// ---------------------------------------------------------------------------
// Fused GAT aggregation (same structure as round 6; ELU now __expf-based).
// ---------------------------------------------------------------------------
template <int H, int FINAL>
__launch_bounds__(256)
__global__ void gat_aggregate(const ushort_t* __restrict__ hWb,
                              const float* __restrict__ alS,
                              const float* __restrict__ alD,
                              const int* __restrict__ rowp,
                              const int* __restrict__ csrc,
                              const float* __restrict__ bias,
                              const ushort_t* __restrict__ resb,
                              ushort_t* __restrict__ outb,
                              float* __restrict__ outf, int n) {
    __shared__ float pbuf[4][64][4];
    __shared__ int obuf[4][64];
    int wid = threadIdx.x >> 6;
    int lane = threadIdx.x & 63;
    int node = blockIdx.x * 4 + wid;
    if (node >= n) return;
    int g = lane >> 4;
    int j = lane & 15;
    int hsel = (H == 4) ? (j >> 2) : 0;
    float ald[4];
    if (H == 4) {
        float4 t = *(const float4*)(alD + (size_t)node * 4);
        ald[0] = t.x; ald[1] = t.y; ald[2] = t.z; ald[3] = t.w;
    } else {
        ald[0] = alD[node];
    }
    int beg = rowp[node], end = rowp[node + 1];
    float zp0 = 0.f, zp1 = 0.f, zp2 = 0.f, zp3 = 0.f;
    float acc[8];
#pragma unroll
    for (int c = 0; c < 8; ++c) acc[c] = 0.f;
    const char* hbase = (const char*)hWb;
    int jo = j << 4;

    for (int base = beg; base < end; base += 64) {
        int nc = min(64, end - base);
        if (lane < nc) {
            int s = csrc[base + lane];
            obuf[wid][lane] = s << 8;
            if (H == 4) {
                float4 t = *(const float4*)(alS + (size_t)s * 4);
                float x0 = t.x + ald[0], x1 = t.y + ald[1];
                float x2 = t.z + ald[2], x3 = t.w + ald[3];
                x0 = (x0 > 0.f) ? x0 : 0.2f * x0;
                x1 = (x1 > 0.f) ? x1 : 0.2f * x1;
                x2 = (x2 > 0.f) ? x2 : 0.2f * x2;
                x3 = (x3 > 0.f) ? x3 : 0.2f * x3;
                float p0 = __expf(x0), p1 = __expf(x1);
                float p2 = __expf(x2), p3 = __expf(x3);
                zp0 += p0; zp1 += p1; zp2 += p2; zp3 += p3;
                float4 t4; t4.x = p0; t4.y = p1; t4.z = p2; t4.w = p3;
                *(float4*)&pbuf[wid][lane][0] = t4;
            } else {
                float x = alS[s] + ald[0];
                x = (x > 0.f) ? x : 0.2f * x;
                float p = __expf(x);
                zp0 += p;
                pbuf[wid][lane][0] = p;
            }
        } else {
            obuf[wid][lane] = node << 8;
            if (H == 4) {
                float4 t4; t4.x = 0.f; t4.y = 0.f; t4.z = 0.f; t4.w = 0.f;
                *(float4*)&pbuf[wid][lane][0] = t4;
            } else {
                pbuf[wid][lane][0] = 0.f;
            }
        }
        int padded = (nc + 7) & ~7;
        for (int i = 0; i < padded; i += 8) {
            int i0 = i + g, i1 = i + 4 + g;
            int o0 = obuf[wid][i0];
            int o1 = obuf[wid][i1];
            float p0 = pbuf[wid][i0][hsel];
            float p1 = pbuf[wid][i1][hsel];
            uint4 h0 = *(const uint4*)(hbase + o0 + jo);
            uint4 h1 = *(const uint4*)(hbase + o1 + jo);
            acc[0] += p0 * bf2f_lo(h0.x); acc[1] += p0 * bf2f_hi_fast(h0.x);
            acc[2] += p0 * bf2f_lo(h0.y); acc[3] += p0 * bf2f_hi_fast(h0.y);
            acc[4] += p0 * bf2f_lo(h0.z); acc[5] += p0 * bf2f_hi_fast(h0.z);
            acc[6] += p0 * bf2f_lo(h0.w); acc[7] += p0 * bf2f_hi_fast(h0.w);
            acc[0] += p1 * bf2f_lo(h1.x); acc[1] += p1 * bf2f_hi_fast(h1.x);
            acc[2] += p1 * bf2f_lo(h1.y); acc[3] += p1 * bf2f_hi_fast(h1.y);
            acc[4] += p1 * bf2f_lo(h1.z); acc[5] += p1 * bf2f_hi_fast(h1.z);
            acc[6] += p1 * bf2f_lo(h1.w); acc[7] += p1 * bf2f_hi_fast(h1.w);
        }
    }

#pragma unroll
    for (int c = 0; c < 8; ++c) {
        acc[c] += __shfl_xor(acc[c], 16, 64);
        acc[c] += __shfl_xor(acc[c], 32, 64);
    }
#pragma unroll
    for (int off = 1; off < 64; off <<= 1) {
        zp0 += __shfl_xor(zp0, off, 64);
        if (H == 4) {
            zp1 += __shfl_xor(zp1, off, 64);
            zp2 += __shfl_xor(zp2, off, 64);
            zp3 += __shfl_xor(zp3, off, 64);
        }
    }
    float zv;
    if (H == 1) zv = zp0;
    else zv = (hsel == 0) ? zp0 : (hsel == 1) ? zp1 : (hsel == 2) ? zp2 : zp3;
    float inv = 1.f / (zv + 1e-16f);

    int c0 = j * 8;
    const float4* bp = (const float4*)(bias + c0);
    float4 bv0 = bp[0], bv1 = bp[1];
    float val[8];
    val[0] = acc[0] * inv + bv0.x; val[1] = acc[1] * inv + bv0.y;
    val[2] = acc[2] * inv + bv0.z; val[3] = acc[3] * inv + bv0.w;
    val[4] = acc[4] * inv + bv1.x; val[5] = acc[5] * inv + bv1.y;
    val[6] = acc[6] * inv + bv1.z; val[7] = acc[7] * inv + bv1.w;
    if (!FINAL) {
        uint4 rv = *((const uint4*)(resb + ((size_t)node << 7)) + j);
        float rr[8] = {bf2f_lo(rv.x), bf2f_hi(rv.x), bf2f_lo(rv.y), bf2f_hi(rv.y),
                       bf2f_lo(rv.z), bf2f_hi(rv.z), bf2f_lo(rv.w), bf2f_hi(rv.w)};
#pragma unroll
        for (int c = 0; c < 8; ++c) {
            float vv = val[c];
            float ev = __expf(vv) - 1.f;   // ELU via fast exp (was expm1f)
            val[c] = ((vv > 0.f) ? vv : ev) + rr[c];
        }
    }
    float s2 = 0.f;
#pragma unroll
    for (int c = 0; c < 8; ++c) s2 += val[c];
#pragma unroll
    for (int off = 1; off < 16; off <<= 1) s2 += __shfl_xor(s2, off, 64);
    float mean = s2 * (1.f / 128.f);
    float q = 0.f;
    float dd[8];
#pragma unroll
    for (int c = 0; c < 8; ++c) {
        dd[c] = val[c] - mean;
        q += dd[c] * dd[c];
    }
#pragma unroll
    for (int off = 1; off < 16; off <<= 1) q += __shfl_xor(q, off, 64);
    float r = rsqrtf(q * (1.f / 128.f) + 1e-5f);
    if (g == 0) {
        if (FINAL) {
            float* op = outf + ((size_t)node << 7) + c0;
            *(float4*)op = make_float4(dd[0] * r, dd[1] * r, dd[2] * r, dd[3] * r);
            *(float4*)(op + 4) = make_float4(dd[4] * r, dd[5] * r, dd[6] * r, dd[7] * r);
        } else {
            uint4 u;
            u.x = (uint_t)f2bf(dd[0] * r) | ((uint_t)f2bf(dd[1] * r) << 16);
            u.y = (uint_t)f2bf(dd[2] * r) | ((uint_t)f2bf(dd[3] * r) << 16);
            u.z = (uint_t)f2bf(dd[4] * r) | ((uint_t)f2bf(dd[5] * r) << 16);
            u.w = (uint_t)f2bf(dd[6] * r) | ((uint_t)f2bf(dd[7] * r) << 16);
            *((uint4*)(outb + ((size_t)node << 7)) + j) = u;
        }
    }
}

// ---------------------------------------------------------------------------
extern "C" void kernel_launch(void* const* d_in, const int* in_sizes, int n_in,
                              void* d_out, int out_size, void* d_ws, size_t ws_size,
                              hipStream_t stream) {
    const int N = in_sizes[0] / 128;
    const int E = in_sizes[1] / 2;
    const int Etot = E + N;
    const int NB = (N + BCK - 1) / BCK;

    const float* x    = (const float*)d_in[0];
    const int*   ei   = (const int*)d_in[1];
    const float* W_in = (const float*)d_in[2];
    const float* b_in = (const float*)d_in[3];
    const float* W0   = (const float*)d_in[4];
    const float* as0  = (const float*)d_in[5];
    const float* ad0  = (const float*)d_in[6];
    const float* b0   = (const float*)d_in[7];
    const float* W1   = (const float*)d_in[8];
    const float* as1  = (const float*)d_in[9];
    const float* ad1  = (const float*)d_in[10];
    const float* b1   = (const float*)d_in[11];
    const float* W2   = (const float*)d_in[12];
    const float* as2  = (const float*)d_in[13];
    const float* ad2  = (const float*)d_in[14];
    const float* b2   = (const float*)d_in[15];

    char* wsp = (char*)d_ws;
    size_t off = 0;
    auto carve = [&](size_t bytes) -> void* {
        void* p = wsp + off;
        off += (bytes + 255) & ~(size_t)255;
        return p;
    };
    ushort_t* hAb  = (ushort_t*)carve((size_t)N * 128 * 2);
    ushort_t* hBb  = (ushort_t*)carve((size_t)N * 128 * 2);
    ushort_t* hWb  = (ushort_t*)carve((size_t)N * 128 * 2);
    float*    alS  = (float*)carve((size_t)N * 4 * 4);
    float*    alD  = (float*)carve((size_t)N * 4 * 4);
    int*      rowp = (int*)carve((size_t)(N + 1) * 4);
    int*      csrc = (int*)carve((size_t)Etot * 4);
    int*      gcnt = (int*)carve((size_t)256 * 4);
    int*      gbase= (int*)carve((size_t)257 * 4);
    int*      gcur = (int*)carve((size_t)256 * 4);
    ushort_t* BfIn = (ushort_t*)carve((size_t)4 * 8 * 64 * 8 * 2);
    ushort_t* Bf0  = (ushort_t*)carve((size_t)4 * 9 * 64 * 8 * 2);
    ushort_t* Bf1  = (ushort_t*)carve((size_t)4 * 9 * 64 * 8 * 2);
    ushort_t* Bf2  = (ushort_t*)carve((size_t)4 * 9 * 64 * 8 * 2);
    // pairs aliases hWb: lifetime ends (bucket_csr) before hWb is written (gemm<1>)
    uint2*    pairs = (uint2*)hWb;
    (void)ws_size; (void)n_in; (void)out_size;

    int gsc = (Etot + 1023) / 1024;

    hipMemsetAsync(gcnt, 0, 256 * 4, stream);
    // bfrag x4 + bucket_count fused
    prep_kernel<<<35 + gsc, 256, 0, stream>>>(W_in, W0, as0, ad0, W1, as1, ad1,
                                              W2, as2, ad2, BfIn, Bf0, Bf1, Bf2,
                                              ei, gcnt, E, N, NB);
    bucket_base<<<1, 256, 0, stream>>>(gcnt, gbase, gcur, rowp, NB, N, Etot);
    bucket_scatter<<<gsc, 256, 0, stream>>>(ei, gcur, pairs, E, N, NB);
    bucket_csr<<<NB, 256, 0, stream>>>(pairs, gbase, rowp, csrc, N);

    int gg = (N + 127) / 128;   // 2 tiles per wave, 4 waves per block
    int ga = (N + 3) / 4;

    // h = relu(x @ W_in + b_in) -> bf16
    gemm_mfma<0><<<gg, 256, 0, stream>>>(x, nullptr, BfIn, b_in, hAb,
                                         nullptr, nullptr, N);
    // Layer 0
    gemm_mfma<1><<<gg, 256, 0, stream>>>(nullptr, hAb, Bf0, nullptr, hWb, alS, alD, N);
    gat_aggregate<4, 0><<<ga, 256, 0, stream>>>(hWb, alS, alD, rowp, csrc, b0,
                                                hAb, hBb, nullptr, N);
    // Layer 1
    gemm_mfma<1><<<gg, 256, 0, stream>>>(nullptr, hBb, Bf1, nullptr, hWb, alS, alD, N);
    gat_aggregate<4, 0><<<ga, 256, 0, stream>>>(hWb, alS, alD, rowp, csrc, b1,
                                                hBb, hAb, nullptr, N);
    // Layer 2 (heads=1)
    gemm_mfma<2><<<gg, 256, 0, stream>>>(nullptr, hAb, Bf2, nullptr, hWb, alS, alD, N);
    gat_aggregate<1, 1><<<ga, 256, 0, stream>>>(hWb, alS, alD, rowp, csrc, b2,
                                                nullptr, nullptr, (float*)d_out, N);
}